// Round 16
// baseline (614.513 us; speedup 1.0000x reference)
//
#include <hip/hip_runtime.h>

#define DIMS 3
#define NB 256
#define NN 256
#define KK 16
#define HID 64
#define EPG 8192
#define NTOT (NB*NN)
#define NE (NB*EPG)

// d_out layout (flat concat of reference outputs, all as float)
#define PX_OFF   0          // (B*K, F, DIMS)           = 786432
#define PEI_OFF  786432     // (2, B*K*K)               = 131072
#define PEA_OFF  917504     // (B*K*K, DIMS)            = 196608
#define PB_OFF   1114112    // (B*K,)                   = 4096
#define LOSS_OFF 1118208    // scalar
#define S_OFF    1118209    // (DIMS, B, N, K)          = 3145728

// d_ws layout (bytes) — total ~27.5 MB
#define WREC_WS  0                 // float[3][NB*EPG] per-d edge weight (CSR order) = 24 MB
#define CLREC_WS 25165824          // uchar[NB*EPG] col-local index
#define IPTR_WS  27262976          // int[NB*257]
#define ENT_WS   27526144          // float[768]
#define MOD_WS   27529216          // float[768]
#define WC_WS    27532288          // float[144*16]  (fcW1 @ fcW2)
#define BC_WS    27541504          // float[16]      (fcb1 @ fcW2 + fcb2)

// ---------------- combined FC weights: Wc = fcW1@fcW2, bc = fcb1@fcW2+fcb2 ----------------
__global__ void fc_combine(const float* __restrict__ fcW1, const float* __restrict__ fcb1,
                           const float* __restrict__ fcW2, const float* __restrict__ fcb2,
                           float* __restrict__ wc, float* __restrict__ bc)
{
    const int t = threadIdx.x;
    for (int idx = t; idx < 144 * 16; idx += 256) {
        const int i = idx >> 4, k = idx & 15;
        float s = 0.f;
        for (int q = 0; q < 50; ++q) s += fcW1[i * 50 + q] * fcW2[q * 16 + k];
        wc[idx] = s;
    }
    if (t < 16) {
        float s = fcb2[t];
        for (int q = 0; q < 50; ++q) s += fcb1[q] * fcW2[q * 16 + t];
        bc[t] = s;
    }
}

// ------- CSR build: parallel deterministic counting sort (strided chunks) -------
#define HSTR 132
#define PSTR 129
__launch_bounds__(256)
__global__ void csr_build(const int* __restrict__ edge_index,
                          const float* __restrict__ edge_attr,
                          float* __restrict__ wrec, unsigned char* __restrict__ clrec,
                          int* __restrict__ indptr)
{
    __shared__ unsigned char  h[256 * HSTR];    // 33.8 KB
    __shared__ unsigned short po[256 * PSTR];   // 66.0 KB
    __shared__ int sc[256];
    const int b = blockIdx.x;
    const int t = threadIdx.x;
    const int* rowp = edge_index + (size_t)b * EPG;
    const int* colp = edge_index + (size_t)NB * EPG + (size_t)b * EPG;

    for (int i = t; i < 256 * HSTR / 4; i += 256) ((unsigned int*)h)[i] = 0u;
    __syncthreads();

    if (t < 128) {
        #pragma unroll 4
        for (int j = 0; j < 64; ++j) {
            const int r = rowp[t + 128 * j] & (NN - 1);
            h[r * HSTR + t]++;
        }
    }
    __syncthreads();

    int tot;
    {
        int s = 0;
        const unsigned int* hr = (const unsigned int*)(h + t * HSTR);
        #pragma unroll
        for (int c4 = 0; c4 < HSTR / 4; ++c4) {
            const unsigned int v = hr[c4];
            s += (v & 255) + ((v >> 8) & 255) + ((v >> 16) & 255) + (v >> 24);
        }
        tot = s;
        sc[t] = s;
    }
    __syncthreads();
    for (int ofs = 1; ofs < 256; ofs <<= 1) {
        int v = (t >= ofs) ? sc[t - ofs] : 0;
        __syncthreads();
        sc[t] += v;
        __syncthreads();
    }
    const int start = sc[t] - tot;
    indptr[b * 257 + t] = start;
    if (t == 255) indptr[b * 257 + 256] = EPG;

    {
        int run = start;
        #pragma unroll 4
        for (int c = 0; c < 128; ++c) {
            po[t * PSTR + c] = (unsigned short)run;
            run += h[t * HSTR + c];
        }
    }
    __syncthreads();

    if (t < 128) {
        const float* eap = edge_attr + (size_t)b * EPG * 3;
        float* w0 = wrec + (size_t)b * EPG;
        float* w1 = wrec + (size_t)NB * EPG + (size_t)b * EPG;
        float* w2 = wrec + 2 * (size_t)NB * EPG + (size_t)b * EPG;
        unsigned char* cdst = clrec + (size_t)b * EPG;
        #pragma unroll 2
        for (int j = 0; j < 64; ++j) {
            const int e = t + 128 * j;
            const int r = rowp[e] & (NN - 1);
            const int cl = colp[e] & (NN - 1);
            const int dest = po[r * PSTR + t]++;
            w0[dest] = eap[e * 3 + 0];
            w1[dest] = eap[e * 3 + 1];
            w2[dest] = eap[e * 3 + 2];
            cdst[dest] = (unsigned char)cl;
        }
    }
}

// -------- gconv v16 = v15 + amdgpu_num_vgpr(48): R14/R15 isolated co-residency to the
// VGPR count (32 fits 2 blocks/CU, 60 does not; 8x64-granule = exactly-full file fails).
// 48 -> 8 waves x 48 = 384 regs/SIMD, clear of any reserved pool, and only 12 below the
// current 60 (mild rescheduling, not bulk spill — unlike (1024,8)'s forced 32). --------
template<int OUTW, bool IS_L2>
__device__ __forceinline__ void layer_step(
    int rp, int o, int fr, int fkq, int js0, int je0, int je1,
    const float* __restrict__ wp, const unsigned char* __restrict__ clp,
    const float* __restrict__ Wm, const float* __restrict__ Ws,
    const float* __restrict__ bias, const float* __restrict__ wc, // wcomb + layer_row_off*16
    float4* hb4, float* p)
{
    constexpr int NCO = OUTW / 8;              // outputs/thread/row: 8 (L0/L1), 2 (L2)
    const int r0 = rp * 2, r1 = r0 + 1;
    const int b0 = r0 * 16, s0 = r0 & 15;
    const int b1 = r1 * 16, s1 = r1 & 15;
    const int c0 = o, c1 = o + 8;              // conflict-free chunk pair

    // P1: gather agg for both rows, channels [4o,4o+4) and [4o+32,4o+36)
    float ga0[8], ga1[8];
    #pragma unroll
    for (int u = 0; u < 8; ++u) { ga0[u] = 0.f; ga1[u] = 0.f; }
    for (int j = js0; j < je0; ++j) {
        const int cl = clp[j];
        const float w = wp[j];
        const int cb = cl * 16, cs = cl & 15;
        const float4 ha = hb4[cb + (c0 ^ cs)];
        const float4 hb = hb4[cb + (c1 ^ cs)];
        ga0[0] += w * ha.x; ga0[1] += w * ha.y; ga0[2] += w * ha.z; ga0[3] += w * ha.w;
        ga0[4] += w * hb.x; ga0[5] += w * hb.y; ga0[6] += w * hb.z; ga0[7] += w * hb.w;
    }
    for (int j = je0; j < je1; ++j) {
        const int cl = clp[j];
        const float w = wp[j];
        const int cb = cl * 16, cs = cl & 15;
        const float4 ha = hb4[cb + (c0 ^ cs)];
        const float4 hb = hb4[cb + (c1 ^ cs)];
        ga1[0] += w * ha.x; ga1[1] += w * ha.y; ga1[2] += w * ha.z; ga1[3] += w * ha.w;
        ga1[4] += w * hb.x; ga1[5] += w * hb.y; ga1[6] += w * hb.z; ga1[7] += w * hb.w;
    }

    // P2: acc = bias + h@Ws (single weight stream from global/L1)
    const int jA = o * 4;                      // column group A
    const int jB = o * 4 + 32;                 // column group B (chunk o+8)
    const int j0L2 = o * NCO;                  // L2 column base
    float acc0[NCO == 8 ? 8 : 2], acc1[NCO == 8 ? 8 : 2];
    if constexpr (NCO == 8) {
        const float4 bv0 = *(const float4*)(bias + jA);
        const float4 bv1 = *(const float4*)(bias + jB);
        acc0[0]=bv0.x; acc0[1]=bv0.y; acc0[2]=bv0.z; acc0[3]=bv0.w;
        acc0[4]=bv1.x; acc0[5]=bv1.y; acc0[6]=bv1.z; acc0[7]=bv1.w;
        #pragma unroll
        for (int u = 0; u < 8; ++u) acc1[u] = acc0[u];
    } else {
        acc0[0] = bias[j0L2]; acc0[1] = bias[j0L2 + 1];
        acc1[0] = acc0[0];    acc1[1] = acc0[1];
    }
    #pragma unroll 1
    for (int ic = 0; ic < 16; ++ic) {
        const float4 h40 = hb4[b0 + (ic ^ s0)];
        const float4 h41 = hb4[b1 + (ic ^ s1)];
        const float hv0[4] = {h40.x, h40.y, h40.z, h40.w};
        const float hv1[4] = {h41.x, h41.y, h41.z, h41.w};
        #pragma unroll
        for (int u = 0; u < 4; ++u) {
            const float* wr = Ws + (ic * 4 + u) * OUTW;
            const float a0 = hv0[u], a1 = hv1[u];
            if constexpr (NCO == 8) {
                const float4 wa = *(const float4*)(wr + jA);
                const float4 wb = *(const float4*)(wr + jB);
                acc0[0]+=a0*wa.x; acc0[1]+=a0*wa.y; acc0[2]+=a0*wa.z; acc0[3]+=a0*wa.w;
                acc0[4]+=a0*wb.x; acc0[5]+=a0*wb.y; acc0[6]+=a0*wb.z; acc0[7]+=a0*wb.w;
                acc1[0]+=a1*wa.x; acc1[1]+=a1*wa.y; acc1[2]+=a1*wa.z; acc1[3]+=a1*wa.w;
                acc1[4]+=a1*wb.x; acc1[5]+=a1*wb.y; acc1[6]+=a1*wb.z; acc1[7]+=a1*wb.w;
            } else {
                const float2 w2 = *(const float2*)(wr + j0L2);
                acc0[0]+=a0*w2.x; acc0[1]+=a0*w2.y;
                acc1[0]+=a1*w2.x; acc1[1]+=a1*w2.y;
            }
        }
    }
    __syncthreads();                           // [B1] all hb reads (gather + P2) done

    // P3: write agg over h (rows r0,r1, chunks o and o+8) — conflict-free
    {
        float4 v;
        v.x = ga0[0]; v.y = ga0[1]; v.z = ga0[2]; v.w = ga0[3]; hb4[b0 + (c0 ^ s0)] = v;
        v.x = ga0[4]; v.y = ga0[5]; v.z = ga0[6]; v.w = ga0[7]; hb4[b0 + (c1 ^ s0)] = v;
        v.x = ga1[0]; v.y = ga1[1]; v.z = ga1[2]; v.w = ga1[3]; hb4[b1 + (c0 ^ s1)] = v;
        v.x = ga1[4]; v.y = ga1[5]; v.z = ga1[6]; v.w = ga1[7]; hb4[b1 + (c1 ^ s1)] = v;
    }
    __syncthreads();                           // [B2] agg visible

    // P4: acc += agg@Wm (single weight stream)
    #pragma unroll 1
    for (int ic = 0; ic < 16; ++ic) {
        const float4 a40 = hb4[b0 + (ic ^ s0)];
        const float4 a41 = hb4[b1 + (ic ^ s1)];
        const float av0[4] = {a40.x, a40.y, a40.z, a40.w};
        const float av1[4] = {a41.x, a41.y, a41.z, a41.w};
        #pragma unroll
        for (int u = 0; u < 4; ++u) {
            const float* wr = Wm + (ic * 4 + u) * OUTW;
            const float a0 = av0[u], a1 = av1[u];
            if constexpr (NCO == 8) {
                const float4 wa = *(const float4*)(wr + jA);
                const float4 wb = *(const float4*)(wr + jB);
                acc0[0]+=a0*wa.x; acc0[1]+=a0*wa.y; acc0[2]+=a0*wa.z; acc0[3]+=a0*wa.w;
                acc0[4]+=a0*wb.x; acc0[5]+=a0*wb.y; acc0[6]+=a0*wb.z; acc0[7]+=a0*wb.w;
                acc1[0]+=a1*wa.x; acc1[1]+=a1*wa.y; acc1[2]+=a1*wa.z; acc1[3]+=a1*wa.w;
                acc1[4]+=a1*wb.x; acc1[5]+=a1*wb.y; acc1[6]+=a1*wb.z; acc1[7]+=a1*wb.w;
            } else {
                const float2 w2 = *(const float2*)(wr + j0L2);
                acc0[0]+=a0*w2.x; acc0[1]+=a0*w2.y;
                acc1[0]+=a1*w2.x; acc1[1]+=a1*w2.y;
            }
        }
    }
    #pragma unroll
    for (int jj = 0; jj < NCO; ++jj) {
        acc0[jj] = fmaxf(acc0[jj], 0.f);
        acc1[jj] = fmaxf(acc1[jj], 0.f);
    }
    __syncthreads();                           // [B3] agg reads done

    // P5: write h_next (L0/L1: cols jA->chunk o, jB->chunk o+8; L2: float2 into chunks 0-3)
    if constexpr (!IS_L2) {
        float4 v;
        v.x = acc0[0]; v.y = acc0[1]; v.z = acc0[2]; v.w = acc0[3]; hb4[b0 + (c0 ^ s0)] = v;
        v.x = acc0[4]; v.y = acc0[5]; v.z = acc0[6]; v.w = acc0[7]; hb4[b0 + (c1 ^ s0)] = v;
        v.x = acc1[0]; v.y = acc1[1]; v.z = acc1[2]; v.w = acc1[3]; hb4[b1 + (c0 ^ s1)] = v;
        v.x = acc1[4]; v.y = acc1[5]; v.z = acc1[6]; v.w = acc1[7]; hb4[b1 + (c1 ^ s1)] = v;
    } else {
        float* hbf = (float*)hb4;
        const int cc = o >> 1, off = (o & 1) * 2;
        float* p0 = hbf + (b0 + (cc ^ s0)) * 4 + off;
        float* p1 = hbf + (b1 + (cc ^ s1)) * 4 + off;
        p0[0] = acc0[0]; p0[1] = acc0[1];
        p1[0] = acc1[0]; p1[1] = acc1[1];
    }
    __syncthreads();                           // [B4] h_next visible

    // FC: thread (fr,fkq) accumulates p[4] += h_next[fr][:] @ Wc[:, fkq*4..+4]
    {
        const int rb = fr * 16, rs = fr & 15;
        if constexpr (!IS_L2) {
            #pragma unroll 2
            for (int c4 = 0; c4 < 16; ++c4) {
                const float4 v4 = hb4[rb + (c4 ^ rs)];
                const float vv[4] = {v4.x, v4.y, v4.z, v4.w};
                #pragma unroll
                for (int e = 0; e < 4; ++e) {
                    const float4 w4 = *(const float4*)(wc + (c4 * 4 + e) * 16 + fkq * 4);
                    p[0] += vv[e] * w4.x; p[1] += vv[e] * w4.y;
                    p[2] += vv[e] * w4.z; p[3] += vv[e] * w4.w;
                }
            }
        } else {
            #pragma unroll 2
            for (int c4 = 0; c4 < 4; ++c4) {
                const float4 v4 = hb4[rb + (c4 ^ rs)];
                const float vv[4] = {v4.x, v4.y, v4.z, v4.w};
                #pragma unroll
                for (int e = 0; e < 4; ++e) {
                    const float4 w4 = *(const float4*)(wc + (c4 * 4 + e) * 16 + fkq * 4);
                    p[0] += vv[e] * w4.x; p[1] += vv[e] * w4.y;
                    p[2] += vv[e] * w4.z; p[3] += vv[e] * w4.w;
                }
            }
        }
    }
    // no trailing barrier: next layer's P1/P2 only READ hb; next P3 writes fenced by next B1.
}

__launch_bounds__(1024)
__attribute__((amdgpu_num_vgpr(48)))
__global__ void gconv_kernel(
    const float* __restrict__ x,
    const float* __restrict__ Wm0, const float* __restrict__ Ws0, const float* __restrict__ b0,
    const float* __restrict__ Wm1, const float* __restrict__ Ws1, const float* __restrict__ b1,
    const float* __restrict__ Wm2, const float* __restrict__ Ws2, const float* __restrict__ b2,
    const float* __restrict__ wcomb, const float* __restrict__ bcomb,
    const float* __restrict__ wrec, const unsigned char* __restrict__ clrec,
    const int* __restrict__ indptr,
    float* __restrict__ out, float* __restrict__ entpart)
{
    __shared__ float4 hb4[4096];       // exactly 64 KB — the ONLY shared buffer
    const int t = threadIdx.x;
    const int bid = blockIdx.x;
    const int d = bid >> 8;
    const int b = bid & (NB - 1);
    const int rp = t >> 3;         // row pair
    const int o = t & 7;           // chunk owner (chunks o, o+8)
    const int fr = t >> 2;         // FC row
    const int fkq = t & 3;         // FC k-quad
    const int lane = t & 63;
    const int wave = t >> 6;

    // stage x -> hb (swizzled)
    {
        const float4* xv = (const float4*)(x + (size_t)b * NN * HID);
        #pragma unroll
        for (int it = 0; it < 4; ++it) {
            const int idx = t + it * 1024;
            const int nrow = idx >> 4, c = idx & 15;
            hb4[nrow * 16 + (c ^ (nrow & 15))] = xv[idx];
        }
    }
    float p[4] = {0.f, 0.f, 0.f, 0.f};   // persistent FC accumulator (thread (fr,fkq))
    __syncthreads();   // [B0]

    const float* wp = wrec + (size_t)d * NB * EPG + (size_t)b * EPG;
    const unsigned char* clp = clrec + (size_t)b * EPG;
    const int js0 = indptr[b * 257 + rp * 2];
    const int je0 = indptr[b * 257 + rp * 2 + 1];
    const int je1 = indptr[b * 257 + rp * 2 + 2];

    layer_step<64, false>(rp, o, fr, fkq, js0, je0, je1, wp, clp, Wm0 + d*HID*HID,
                          Ws0 + d*HID*HID, b0 + d*HID, wcomb,          hb4, p);
    layer_step<64, false>(rp, o, fr, fkq, js0, je0, je1, wp, clp, Wm1 + d*HID*HID,
                          Ws1 + d*HID*HID, b1 + d*HID, wcomb + 64*16,  hb4, p);
    layer_step<16, true >(rp, o, fr, fkq, js0, je0, je1, wp, clp, Wm2 + d*HID*KK,
                          Ws2 + d*HID*KK,  b2 + d*KK,  wcomb + 128*16, hb4, p);

    __syncthreads();   // [B5] all FC reads of hb done — safe to overwrite with logits
    {
        float* hbf = (float*)hb4;
        float* dst = hbf + fr * 17 + fkq * 4;    // logits region: floats [0, 4352)
        dst[0] = p[0]; dst[1] = p[1]; dst[2] = p[2]; dst[3] = p[3];
    }
    __syncthreads();   // [B6] logits visible

    // softmax + entropy: threads t<256, row = t
    float ent_local = 0.f;
    if (t < 256) {
        const int rr = t;
        const float* Lr = (const float*)hb4 + rr * 17;
        float logits[KK];
        #pragma unroll
        for (int k = 0; k < KK; ++k) logits[k] = Lr[k] + bcomb[k];
        float m = logits[0];
        #pragma unroll
        for (int k = 1; k < KK; ++k) m = fmaxf(m, logits[k]);
        float sum = 0.f, sv[KK];
        #pragma unroll
        for (int k = 0; k < KK; ++k) { sv[k] = expf(logits[k] - m); sum += sv[k]; }
        const float inv = 1.f / sum;
        float4* sp4 = (float4*)(out + S_OFF + ((size_t)(d * NB + b) * NN + rr) * KK);
        #pragma unroll
        for (int q4 = 0; q4 < 4; ++q4) {
            float4 v;
            const float s0 = sv[q4*4+0] * inv, s1 = sv[q4*4+1] * inv;
            const float s2 = sv[q4*4+2] * inv, s3 = sv[q4*4+3] * inv;
            v.x = s0; v.y = s1; v.z = s2; v.w = s3;
            sp4[q4] = v;
            ent_local -= s0 * logf(s0 + 1e-15f) + s1 * logf(s1 + 1e-15f)
                       + s2 * logf(s2 + 1e-15f) + s3 * logf(s3 + 1e-15f);
        }
    }
    #pragma unroll
    for (int off = 32; off; off >>= 1) ent_local += __shfl_down(ent_local, off);
    // red scratch lives in hb floats [8192, 8208) — disjoint from logits region [0,4352)
    {
        float* redf = (float*)hb4 + 8192;
        if (lane == 0) redf[wave] = ent_local;
        __syncthreads();
        if (t == 0) {
            float s = 0.f;
            #pragma unroll
            for (int w = 0; w < 16; ++w) s += redf[w];
            entpart[bid] = s;
        }
    }
}

// ---------------- pool: padj = sum_r s[r] (x) G[r], G = A s ; + mod + px ----------------
#define SSTR 20
__launch_bounds__(256)
__global__ void pool_kernel(
    const float* __restrict__ x_to_pool,
    const float* __restrict__ wrec, const unsigned char* __restrict__ clrec,
    const int* __restrict__ indptr,
    const float* __restrict__ out_s, float* __restrict__ out, float* __restrict__ modpart)
{
    __shared__ float sl[NN * SSTR];       // 20 KB
    __shared__ float gl[NN * SSTR];       // 20 KB
    __shared__ float padjw[4 * 256];      // per-wave partials (deterministic merge)
    __shared__ float red[4];
    const int t = threadIdx.x;
    const int bid = blockIdx.x;
    const int d = bid >> 8;
    const int b = bid & (NB - 1);
    const int lane = t & 63;
    const int wave = t >> 6;

    {
        const float4* sp4 = (const float4*)(out_s + S_OFF + (size_t)(d * NB + b) * NN * KK);
        #pragma unroll
        for (int it = 0; it < 4; ++it) {
            const int idx = t + it * 256;
            const int nrow = idx >> 2, c = idx & 3;
            *(float4*)(sl + nrow * SSTR + c * 4) = sp4[idx];
        }
    }
    __syncthreads();

    const float* wp = wrec + (size_t)d * NB * EPG + (size_t)b * EPG;
    const unsigned char* clp = clrec + (size_t)b * EPG;
    const int js = indptr[b * 257 + t];
    const int je = indptr[b * 257 + t + 1];
    float sr[16];
    {
        #pragma unroll
        for (int c = 0; c < 4; ++c) {
            const float4 v = *(const float4*)(sl + t * SSTR + c * 4);
            sr[c*4+0] = v.x; sr[c*4+1] = v.y; sr[c*4+2] = v.z; sr[c*4+3] = v.w;
        }
    }
    float g[16];
    #pragma unroll
    for (int k = 0; k < 16; ++k) g[k] = 0.f;
    float modacc = 0.f;
    for (int j = js; j < je; ++j) {
        const int cl = clp[j];
        const float w = wp[j];
        const float* srow = sl + cl * SSTR;
        float ss = 0.f;
        #pragma unroll
        for (int c = 0; c < 4; ++c) {
            const float4 sv = *(const float4*)(srow + c * 4);
            g[c*4+0] += w * sv.x; g[c*4+1] += w * sv.y;
            g[c*4+2] += w * sv.z; g[c*4+3] += w * sv.w;
            const float d0 = sr[c*4+0] - sv.x, d1 = sr[c*4+1] - sv.y;
            const float d2 = sr[c*4+2] - sv.z, d3 = sr[c*4+3] - sv.w;
            ss += d0*d0 + d1*d1 + d2*d2 + d3*d3;
        }
        modacc += w * ss;
    }
    {
        #pragma unroll
        for (int c = 0; c < 4; ++c) {
            float4 v; v.x = g[c*4+0]; v.y = g[c*4+1]; v.z = g[c*4+2]; v.w = g[c*4+3];
            *(float4*)(gl + t * SSTR + c * 4) = v;
        }
    }
    __syncthreads();

    {
        const int k = t & 15, lg = (t >> 4) & 3;
        float p0 = 0.f, p1 = 0.f, p2 = 0.f, p3 = 0.f;
        const int r0 = wave * 64;
        for (int rr = r0; rr < r0 + 64; ++rr) {
            const float sk = sl[rr * SSTR + k];
            const float4 g4 = *(const float4*)(gl + rr * SSTR + lg * 4);
            p0 += sk * g4.x; p1 += sk * g4.y; p2 += sk * g4.z; p3 += sk * g4.w;
        }
        float* pw = padjw + wave * 256 + k * 16 + lg * 4;
        pw[0] = p0; pw[1] = p1; pw[2] = p2; pw[3] = p3;
    }

    {
        const int f = t & 63;
        const int kg = t >> 6;
        float xa0 = 0.f, xa1 = 0.f, xa2 = 0.f, xa3 = 0.f;
        const float* xp = x_to_pool + (size_t)b * NN * (64 * DIMS) + f * DIMS + d;
        #pragma unroll 4
        for (int nn2 = 0; nn2 < NN; ++nn2) {
            const float xv = xp[(size_t)nn2 * (64 * DIMS)];
            const float4 s4 = *(const float4*)(sl + nn2 * SSTR + kg * 4);
            xa0 += xv * s4.x; xa1 += xv * s4.y; xa2 += xv * s4.z; xa3 += xv * s4.w;
        }
        const float sc = 1.f / 16.f;  // K/N
        out[PX_OFF + ((size_t)((b * KK + kg * 4 + 0) * 64) + f) * DIMS + d] = xa0 * sc;
        out[PX_OFF + ((size_t)((b * KK + kg * 4 + 1) * 64) + f) * DIMS + d] = xa1 * sc;
        out[PX_OFF + ((size_t)((b * KK + kg * 4 + 2) * 64) + f) * DIMS + d] = xa2 * sc;
        out[PX_OFF + ((size_t)((b * KK + kg * 4 + 3) * 64) + f) * DIMS + d] = xa3 * sc;
    }

    #pragma unroll
    for (int off = 32; off; off >>= 1) modacc += __shfl_down(modacc, off);
    if (lane == 0) red[wave] = modacc;
    __syncthreads();
    if (t == 0) modpart[bid] = red[0] + red[1] + red[2] + red[3];

    {
        const float v = (padjw[t] + padjw[256 + t] + padjw[512 + t] + padjw[768 + t]) * (1.f / 256.f);
        out[PEA_OFF + (size_t)((b * KK + (t >> 4)) * KK + (t & 15)) * DIMS + d] = v;
    }
}

__global__ void aux_kernel(float* __restrict__ out)
{
    const int idx = blockIdx.x * 256 + threadIdx.x;
    if (idx < 2 * NTOT) {
        const int r = idx & (NTOT - 1);
        const int bb = r >> 8;
        const int j = r & 255;
        const int v = (idx < NTOT) ? (bb * KK + (j >> 4)) : (bb * KK + (j & 15));
        out[PEI_OFF + idx] = (float)v;
    } else if (idx < 2 * NTOT + NB * KK) {
        const int i = idx - 2 * NTOT;
        out[PB_OFF + i] = (float)(i >> 4);
    }
}

__global__ void loss_kernel(const float* __restrict__ entpart,
                            const float* __restrict__ modpart,
                            float* __restrict__ out)
{
    const int tid = threadIdx.x;
    float e = 0.f, m = 0.f;
    for (int i = tid; i < DIMS * NB; i += 256) { e += entpart[i]; m += modpart[i]; }
    #pragma unroll
    for (int off = 32; off; off >>= 1) { e += __shfl_down(e, off); m += __shfl_down(m, off); }
    __shared__ float er[4], mr[4];
    const int wave = tid >> 6, lane = tid & 63;
    if (lane == 0) { er[wave] = e; mr[wave] = m; }
    __syncthreads();
    if (tid == 0) {
        const float es = er[0] + er[1] + er[2] + er[3];
        const float ms = mr[0] + mr[1] + mr[2] + mr[3];
        out[LOSS_OFF] = ms / (float)NE + es / (float)(DIMS * NTOT);
    }
}

extern "C" void kernel_launch(void* const* d_in, const int* in_sizes, int n_in,
                              void* d_out, int out_size, void* d_ws, size_t ws_size,
                              hipStream_t stream)
{
    const float* x         = (const float*)d_in[0];
    const float* edge_attr = (const float*)d_in[1];
    const float* x_to_pool = (const float*)d_in[2];
    const float* Wm0 = (const float*)d_in[3];
    const float* Ws0 = (const float*)d_in[4];
    const float* b0  = (const float*)d_in[5];
    const float* Wm1 = (const float*)d_in[6];
    const float* Ws1 = (const float*)d_in[7];
    const float* b1  = (const float*)d_in[8];
    const float* Wm2 = (const float*)d_in[9];
    const float* Ws2 = (const float*)d_in[10];
    const float* b2  = (const float*)d_in[11];
    const float* fcW1= (const float*)d_in[12];
    const float* fcb1= (const float*)d_in[13];
    const float* fcW2= (const float*)d_in[14];
    const float* fcb2= (const float*)d_in[15];
    const int* edge_index = (const int*)d_in[16];
    float* out = (float*)d_out;
    char* ws = (char*)d_ws;
    float*         wrec  = (float*)(ws + WREC_WS);
    unsigned char* clrec = (unsigned char*)(ws + CLREC_WS);
    int*           iptr  = (int*)(ws + IPTR_WS);
    float*         entpart = (float*)(ws + ENT_WS);
    float*         modpart = (float*)(ws + MOD_WS);
    float*         wc    = (float*)(ws + WC_WS);
    float*         bc    = (float*)(ws + BC_WS);

    csr_build<<<dim3(NB), dim3(256), 0, stream>>>(edge_index, edge_attr, wrec, clrec, iptr);
    fc_combine<<<dim3(1), dim3(256), 0, stream>>>(fcW1, fcb1, fcW2, fcb2, wc, bc);
    gconv_kernel<<<dim3(DIMS * NB), dim3(1024), 0, stream>>>(
        x, Wm0, Ws0, b0, Wm1, Ws1, b1, Wm2, Ws2, b2,
        wc, bc, wrec, clrec, iptr, out, entpart);
    pool_kernel<<<dim3(DIMS * NB), dim3(256), 0, stream>>>(
        x_to_pool, wrec, clrec, iptr, out, out, modpart);
    aux_kernel<<<dim3((2 * NTOT + NB * KK + 255) / 256), dim3(256), 0, stream>>>(out);
    loss_kernel<<<dim3(1), dim3(256), 0, stream>>>(entpart, modpart, out);
}

// Round 17
// 575.574 us; speedup vs baseline: 1.0677x; 1.0677x over previous
//
#include <hip/hip_runtime.h>

#define DIMS 3
#define NB 256
#define NN 256
#define KK 16
#define HID 64
#define EPG 8192
#define NTOT (NB*NN)
#define NE (NB*EPG)

// d_out layout (flat concat of reference outputs, all as float)
#define PX_OFF   0          // (B*K, F, DIMS)           = 786432
#define PEI_OFF  786432     // (2, B*K*K)               = 131072
#define PEA_OFF  917504     // (B*K*K, DIMS)            = 196608
#define PB_OFF   1114112    // (B*K,)                   = 4096
#define LOSS_OFF 1118208    // scalar
#define S_OFF    1118209    // (DIMS, B, N, K)          = 3145728

// d_ws layout (bytes) — total ~27.5 MB
#define WREC_WS  0                 // float[3][NB*EPG] per-d edge weight (CSR order) = 24 MB
#define CLREC_WS 25165824          // uchar[NB*EPG] col-local index
#define IPTR_WS  27262976          // int[NB*257]
#define ENT_WS   27526144          // float[768]
#define MOD_WS   27529216          // float[768]
#define WC_WS    27532288          // float[144*16]  (fcW1 @ fcW2)
#define BC_WS    27541504          // float[16]      (fcb1 @ fcW2 + fcb2)

// LDS float-offsets inside hb (16384 floats) for the fused pool epilogue
#define SL_OFF   0         // s tile      [256][20]  -> [0, 5120)
#define GL_OFF   5120      // G tile      [256][20]  -> [5120, 10240)
#define PXP_OFF  10240     // px partials [16][64][4]-> [10240, 14336)
#define PJW_OFF  14336     // padj part.  [4][256]   -> [14336, 15360)
#define MRED_OFF 15360     // mod red     [16]
#define ERED_OFF 15380     // ent red     [16]

// ---------------- combined FC weights: Wc = fcW1@fcW2, bc = fcb1@fcW2+fcb2 ----------------
__global__ void fc_combine(const float* __restrict__ fcW1, const float* __restrict__ fcb1,
                           const float* __restrict__ fcW2, const float* __restrict__ fcb2,
                           float* __restrict__ wc, float* __restrict__ bc)
{
    const int t = threadIdx.x;
    for (int idx = t; idx < 144 * 16; idx += 256) {
        const int i = idx >> 4, k = idx & 15;
        float s = 0.f;
        for (int q = 0; q < 50; ++q) s += fcW1[i * 50 + q] * fcW2[q * 16 + k];
        wc[idx] = s;
    }
    if (t < 16) {
        float s = fcb2[t];
        for (int q = 0; q < 50; ++q) s += fcb1[q] * fcW2[q * 16 + t];
        bc[t] = s;
    }
}

// ------- CSR build: parallel deterministic counting sort (strided chunks) -------
#define HSTR 132
#define PSTR 129
__launch_bounds__(256)
__global__ void csr_build(const int* __restrict__ edge_index,
                          const float* __restrict__ edge_attr,
                          float* __restrict__ wrec, unsigned char* __restrict__ clrec,
                          int* __restrict__ indptr)
{
    __shared__ unsigned char  h[256 * HSTR];    // 33.8 KB
    __shared__ unsigned short po[256 * PSTR];   // 66.0 KB
    __shared__ int sc[256];
    const int b = blockIdx.x;
    const int t = threadIdx.x;
    const int* rowp = edge_index + (size_t)b * EPG;
    const int* colp = edge_index + (size_t)NB * EPG + (size_t)b * EPG;

    for (int i = t; i < 256 * HSTR / 4; i += 256) ((unsigned int*)h)[i] = 0u;
    __syncthreads();

    if (t < 128) {
        #pragma unroll 4
        for (int j = 0; j < 64; ++j) {
            const int r = rowp[t + 128 * j] & (NN - 1);
            h[r * HSTR + t]++;
        }
    }
    __syncthreads();

    int tot;
    {
        int s = 0;
        const unsigned int* hr = (const unsigned int*)(h + t * HSTR);
        #pragma unroll
        for (int c4 = 0; c4 < HSTR / 4; ++c4) {
            const unsigned int v = hr[c4];
            s += (v & 255) + ((v >> 8) & 255) + ((v >> 16) & 255) + (v >> 24);
        }
        tot = s;
        sc[t] = s;
    }
    __syncthreads();
    for (int ofs = 1; ofs < 256; ofs <<= 1) {
        int v = (t >= ofs) ? sc[t - ofs] : 0;
        __syncthreads();
        sc[t] += v;
        __syncthreads();
    }
    const int start = sc[t] - tot;
    indptr[b * 257 + t] = start;
    if (t == 255) indptr[b * 257 + 256] = EPG;

    {
        int run = start;
        #pragma unroll 4
        for (int c = 0; c < 128; ++c) {
            po[t * PSTR + c] = (unsigned short)run;
            run += h[t * HSTR + c];
        }
    }
    __syncthreads();

    if (t < 128) {
        const float* eap = edge_attr + (size_t)b * EPG * 3;
        float* w0 = wrec + (size_t)b * EPG;
        float* w1 = wrec + (size_t)NB * EPG + (size_t)b * EPG;
        float* w2 = wrec + 2 * (size_t)NB * EPG + (size_t)b * EPG;
        unsigned char* cdst = clrec + (size_t)b * EPG;
        #pragma unroll 2
        for (int j = 0; j < 64; ++j) {
            const int e = t + 128 * j;
            const int r = rowp[e] & (NN - 1);
            const int cl = colp[e] & (NN - 1);
            const int dest = po[r * PSTR + t]++;
            w0[dest] = eap[e * 3 + 0];
            w1[dest] = eap[e * 3 + 1];
            w2[dest] = eap[e * 3 + 2];
            cdst[dest] = (unsigned char)cl;
        }
    }
}

// -------- gconv v17 = v15 (456 us base, 60 VGPR, no spill) + FUSED POOL epilogue.
// Pool phases run on the same 1024 threads reusing the dead 64 KB h buffer:
//   s -> LDS [256][20]; G=A*s + mod (thread=(row,kquad)); padj partials
//   (thread=(q,k,l)); px partials (thread=(rg,kg,f), 64 iters); deterministic merges. --------
template<int OUTW, bool IS_L2>
__device__ __forceinline__ void layer_step(
    int rp, int o, int fr, int fkq, int js0, int je0, int je1,
    const float* __restrict__ wp, const unsigned char* __restrict__ clp,
    const float* __restrict__ Wm, const float* __restrict__ Ws,
    const float* __restrict__ bias, const float* __restrict__ wc, // wcomb + layer_row_off*16
    float4* hb4, float* p)
{
    constexpr int NCO = OUTW / 8;              // outputs/thread/row: 8 (L0/L1), 2 (L2)
    const int r0 = rp * 2, r1 = r0 + 1;
    const int b0 = r0 * 16, s0 = r0 & 15;
    const int b1 = r1 * 16, s1 = r1 & 15;
    const int c0 = o, c1 = o + 8;              // conflict-free chunk pair

    // P1: gather agg for both rows, channels [4o,4o+4) and [4o+32,4o+36)
    float ga0[8], ga1[8];
    #pragma unroll
    for (int u = 0; u < 8; ++u) { ga0[u] = 0.f; ga1[u] = 0.f; }
    for (int j = js0; j < je0; ++j) {
        const int cl = clp[j];
        const float w = wp[j];
        const int cb = cl * 16, cs = cl & 15;
        const float4 ha = hb4[cb + (c0 ^ cs)];
        const float4 hb = hb4[cb + (c1 ^ cs)];
        ga0[0] += w * ha.x; ga0[1] += w * ha.y; ga0[2] += w * ha.z; ga0[3] += w * ha.w;
        ga0[4] += w * hb.x; ga0[5] += w * hb.y; ga0[6] += w * hb.z; ga0[7] += w * hb.w;
    }
    for (int j = je0; j < je1; ++j) {
        const int cl = clp[j];
        const float w = wp[j];
        const int cb = cl * 16, cs = cl & 15;
        const float4 ha = hb4[cb + (c0 ^ cs)];
        const float4 hb = hb4[cb + (c1 ^ cs)];
        ga1[0] += w * ha.x; ga1[1] += w * ha.y; ga1[2] += w * ha.z; ga1[3] += w * ha.w;
        ga1[4] += w * hb.x; ga1[5] += w * hb.y; ga1[6] += w * hb.z; ga1[7] += w * hb.w;
    }

    // P2: acc = bias + h@Ws (single weight stream from global/L1)
    const int jA = o * 4;
    const int jB = o * 4 + 32;
    const int j0L2 = o * NCO;
    float acc0[NCO == 8 ? 8 : 2], acc1[NCO == 8 ? 8 : 2];
    if constexpr (NCO == 8) {
        const float4 bv0 = *(const float4*)(bias + jA);
        const float4 bv1 = *(const float4*)(bias + jB);
        acc0[0]=bv0.x; acc0[1]=bv0.y; acc0[2]=bv0.z; acc0[3]=bv0.w;
        acc0[4]=bv1.x; acc0[5]=bv1.y; acc0[6]=bv1.z; acc0[7]=bv1.w;
        #pragma unroll
        for (int u = 0; u < 8; ++u) acc1[u] = acc0[u];
    } else {
        acc0[0] = bias[j0L2]; acc0[1] = bias[j0L2 + 1];
        acc1[0] = acc0[0];    acc1[1] = acc0[1];
    }
    #pragma unroll 1
    for (int ic = 0; ic < 16; ++ic) {
        const float4 h40 = hb4[b0 + (ic ^ s0)];
        const float4 h41 = hb4[b1 + (ic ^ s1)];
        const float hv0[4] = {h40.x, h40.y, h40.z, h40.w};
        const float hv1[4] = {h41.x, h41.y, h41.z, h41.w};
        #pragma unroll
        for (int u = 0; u < 4; ++u) {
            const float* wr = Ws + (ic * 4 + u) * OUTW;
            const float a0 = hv0[u], a1 = hv1[u];
            if constexpr (NCO == 8) {
                const float4 wa = *(const float4*)(wr + jA);
                const float4 wb = *(const float4*)(wr + jB);
                acc0[0]+=a0*wa.x; acc0[1]+=a0*wa.y; acc0[2]+=a0*wa.z; acc0[3]+=a0*wa.w;
                acc0[4]+=a0*wb.x; acc0[5]+=a0*wb.y; acc0[6]+=a0*wb.z; acc0[7]+=a0*wb.w;
                acc1[0]+=a1*wa.x; acc1[1]+=a1*wa.y; acc1[2]+=a1*wa.z; acc1[3]+=a1*wa.w;
                acc1[4]+=a1*wb.x; acc1[5]+=a1*wb.y; acc1[6]+=a1*wb.z; acc1[7]+=a1*wb.w;
            } else {
                const float2 w2 = *(const float2*)(wr + j0L2);
                acc0[0]+=a0*w2.x; acc0[1]+=a0*w2.y;
                acc1[0]+=a1*w2.x; acc1[1]+=a1*w2.y;
            }
        }
    }
    __syncthreads();                           // [B1] all hb reads (gather + P2) done

    // P3: write agg over h
    {
        float4 v;
        v.x = ga0[0]; v.y = ga0[1]; v.z = ga0[2]; v.w = ga0[3]; hb4[b0 + (c0 ^ s0)] = v;
        v.x = ga0[4]; v.y = ga0[5]; v.z = ga0[6]; v.w = ga0[7]; hb4[b0 + (c1 ^ s0)] = v;
        v.x = ga1[0]; v.y = ga1[1]; v.z = ga1[2]; v.w = ga1[3]; hb4[b1 + (c0 ^ s1)] = v;
        v.x = ga1[4]; v.y = ga1[5]; v.z = ga1[6]; v.w = ga1[7]; hb4[b1 + (c1 ^ s1)] = v;
    }
    __syncthreads();                           // [B2] agg visible

    // P4: acc += agg@Wm
    #pragma unroll 1
    for (int ic = 0; ic < 16; ++ic) {
        const float4 a40 = hb4[b0 + (ic ^ s0)];
        const float4 a41 = hb4[b1 + (ic ^ s1)];
        const float av0[4] = {a40.x, a40.y, a40.z, a40.w};
        const float av1[4] = {a41.x, a41.y, a41.z, a41.w};
        #pragma unroll
        for (int u = 0; u < 4; ++u) {
            const float* wr = Wm + (ic * 4 + u) * OUTW;
            const float a0 = av0[u], a1 = av1[u];
            if constexpr (NCO == 8) {
                const float4 wa = *(const float4*)(wr + jA);
                const float4 wb = *(const float4*)(wr + jB);
                acc0[0]+=a0*wa.x; acc0[1]+=a0*wa.y; acc0[2]+=a0*wa.z; acc0[3]+=a0*wa.w;
                acc0[4]+=a0*wb.x; acc0[5]+=a0*wb.y; acc0[6]+=a0*wb.z; acc0[7]+=a0*wb.w;
                acc1[0]+=a1*wa.x; acc1[1]+=a1*wa.y; acc1[2]+=a1*wa.z; acc1[3]+=a1*wa.w;
                acc1[4]+=a1*wb.x; acc1[5]+=a1*wb.y; acc1[6]+=a1*wb.z; acc1[7]+=a1*wb.w;
            } else {
                const float2 w2 = *(const float2*)(wr + j0L2);
                acc0[0]+=a0*w2.x; acc0[1]+=a0*w2.y;
                acc1[0]+=a1*w2.x; acc1[1]+=a1*w2.y;
            }
        }
    }
    #pragma unroll
    for (int jj = 0; jj < NCO; ++jj) {
        acc0[jj] = fmaxf(acc0[jj], 0.f);
        acc1[jj] = fmaxf(acc1[jj], 0.f);
    }
    __syncthreads();                           // [B3] agg reads done

    // P5: write h_next
    if constexpr (!IS_L2) {
        float4 v;
        v.x = acc0[0]; v.y = acc0[1]; v.z = acc0[2]; v.w = acc0[3]; hb4[b0 + (c0 ^ s0)] = v;
        v.x = acc0[4]; v.y = acc0[5]; v.z = acc0[6]; v.w = acc0[7]; hb4[b0 + (c1 ^ s0)] = v;
        v.x = acc1[0]; v.y = acc1[1]; v.z = acc1[2]; v.w = acc1[3]; hb4[b1 + (c0 ^ s1)] = v;
        v.x = acc1[4]; v.y = acc1[5]; v.z = acc1[6]; v.w = acc1[7]; hb4[b1 + (c1 ^ s1)] = v;
    } else {
        float* hbf = (float*)hb4;
        const int cc = o >> 1, off = (o & 1) * 2;
        float* p0 = hbf + (b0 + (cc ^ s0)) * 4 + off;
        float* p1 = hbf + (b1 + (cc ^ s1)) * 4 + off;
        p0[0] = acc0[0]; p0[1] = acc0[1];
        p1[0] = acc1[0]; p1[1] = acc1[1];
    }
    __syncthreads();                           // [B4] h_next visible

    // FC: thread (fr,fkq) accumulates p[4] += h_next[fr][:] @ Wc[:, fkq*4..+4]
    {
        const int rb = fr * 16, rs = fr & 15;
        if constexpr (!IS_L2) {
            #pragma unroll 2
            for (int c4 = 0; c4 < 16; ++c4) {
                const float4 v4 = hb4[rb + (c4 ^ rs)];
                const float vv[4] = {v4.x, v4.y, v4.z, v4.w};
                #pragma unroll
                for (int e = 0; e < 4; ++e) {
                    const float4 w4 = *(const float4*)(wc + (c4 * 4 + e) * 16 + fkq * 4);
                    p[0] += vv[e] * w4.x; p[1] += vv[e] * w4.y;
                    p[2] += vv[e] * w4.z; p[3] += vv[e] * w4.w;
                }
            }
        } else {
            #pragma unroll 2
            for (int c4 = 0; c4 < 4; ++c4) {
                const float4 v4 = hb4[rb + (c4 ^ rs)];
                const float vv[4] = {v4.x, v4.y, v4.z, v4.w};
                #pragma unroll
                for (int e = 0; e < 4; ++e) {
                    const float4 w4 = *(const float4*)(wc + (c4 * 4 + e) * 16 + fkq * 4);
                    p[0] += vv[e] * w4.x; p[1] += vv[e] * w4.y;
                    p[2] += vv[e] * w4.z; p[3] += vv[e] * w4.w;
                }
            }
        }
    }
}

__launch_bounds__(1024)
__global__ void gconv_kernel(
    const float* __restrict__ x,
    const float* __restrict__ x_to_pool,
    const float* __restrict__ Wm0, const float* __restrict__ Ws0, const float* __restrict__ b0,
    const float* __restrict__ Wm1, const float* __restrict__ Ws1, const float* __restrict__ b1,
    const float* __restrict__ Wm2, const float* __restrict__ Ws2, const float* __restrict__ b2,
    const float* __restrict__ wcomb, const float* __restrict__ bcomb,
    const float* __restrict__ wrec, const unsigned char* __restrict__ clrec,
    const int* __restrict__ indptr,
    float* __restrict__ out, float* __restrict__ entpart, float* __restrict__ modpart)
{
    __shared__ float4 hb4[4096];       // exactly 64 KB — reused by the pool epilogue
    float* hbf = (float*)hb4;
    const int t = threadIdx.x;
    const int bid = blockIdx.x;
    const int d = bid >> 8;
    const int b = bid & (NB - 1);
    const int rp = t >> 3;         // row pair
    const int o = t & 7;           // chunk owner (chunks o, o+8)
    const int fr = t >> 2;         // FC row
    const int fkq = t & 3;         // FC k-quad
    const int lane = t & 63;
    const int wave = t >> 6;

    // stage x -> hb (swizzled)
    {
        const float4* xv = (const float4*)(x + (size_t)b * NN * HID);
        #pragma unroll
        for (int it = 0; it < 4; ++it) {
            const int idx = t + it * 1024;
            const int nrow = idx >> 4, c = idx & 15;
            hb4[nrow * 16 + (c ^ (nrow & 15))] = xv[idx];
        }
    }
    float p[4] = {0.f, 0.f, 0.f, 0.f};
    __syncthreads();   // [B0]

    const float* wp = wrec + (size_t)d * NB * EPG + (size_t)b * EPG;
    const unsigned char* clp = clrec + (size_t)b * EPG;
    const int* ipb = indptr + b * 257;
    const int js0 = ipb[rp * 2];
    const int je0 = ipb[rp * 2 + 1];
    const int je1 = ipb[rp * 2 + 2];

    layer_step<64, false>(rp, o, fr, fkq, js0, je0, je1, wp, clp, Wm0 + d*HID*HID,
                          Ws0 + d*HID*HID, b0 + d*HID, wcomb,          hb4, p);
    layer_step<64, false>(rp, o, fr, fkq, js0, je0, je1, wp, clp, Wm1 + d*HID*HID,
                          Ws1 + d*HID*HID, b1 + d*HID, wcomb + 64*16,  hb4, p);
    layer_step<16, true >(rp, o, fr, fkq, js0, je0, je1, wp, clp, Wm2 + d*HID*KK,
                          Ws2 + d*HID*KK,  b2 + d*KK,  wcomb + 128*16, hb4, p);

    __syncthreads();   // [B5] FC reads done — hb reusable
    // logits -> [r][20] region
    {
        float* dst = hbf + SL_OFF + fr * 20 + fkq * 4;
        dst[0] = p[0]; dst[1] = p[1]; dst[2] = p[2]; dst[3] = p[3];
    }
    __syncthreads();   // [B6] logits visible

    // softmax + entropy (t<256); s overwrites logits region; s also -> out
    float ent_local = 0.f;
    if (t < 256) {
        const int rr = t;
        float* Lr = hbf + SL_OFF + rr * 20;
        float logits[KK];
        #pragma unroll
        for (int k = 0; k < KK; ++k) logits[k] = Lr[k] + bcomb[k];
        float m = logits[0];
        #pragma unroll
        for (int k = 1; k < KK; ++k) m = fmaxf(m, logits[k]);
        float sum = 0.f, sv[KK];
        #pragma unroll
        for (int k = 0; k < KK; ++k) { sv[k] = expf(logits[k] - m); sum += sv[k]; }
        const float inv = 1.f / sum;
        float4* sp4 = (float4*)(out + S_OFF + ((size_t)(d * NB + b) * NN + rr) * KK);
        #pragma unroll
        for (int q4 = 0; q4 < 4; ++q4) {
            float4 v;
            const float s0 = sv[q4*4+0] * inv, s1 = sv[q4*4+1] * inv;
            const float s2 = sv[q4*4+2] * inv, s3 = sv[q4*4+3] * inv;
            v.x = s0; v.y = s1; v.z = s2; v.w = s3;
            sp4[q4] = v;
            *(float4*)(Lr + q4 * 4) = v;          // s into LDS
            ent_local -= s0 * logf(s0 + 1e-15f) + s1 * logf(s1 + 1e-15f)
                       + s2 * logf(s2 + 1e-15f) + s3 * logf(s3 + 1e-15f);
        }
    }
    #pragma unroll
    for (int off = 32; off; off >>= 1) ent_local += __shfl_down(ent_local, off);
    if (lane == 0) hbf[ERED_OFF + wave] = ent_local;
    __syncthreads();   // [B7] s + ent partials visible
    if (t == 0) {
        float s = 0.f;
        #pragma unroll
        for (int w = 0; w < 16; ++w) s += hbf[ERED_OFF + w];
        entpart[bid] = s;
    }

    // ---- fused pool ----
    // Phase A: G = A*s (thread=(row pr, kquad pkq)) + modularity partial
    {
        const int pr = t >> 2, pkq = t & 3;
        const int pjs = ipb[pr], pje = ipb[pr + 1];
        const float4 sq = *(const float4*)(hbf + SL_OFF + pr * 20 + pkq * 4);
        float g0 = 0.f, g1 = 0.f, g2 = 0.f, g3 = 0.f;
        float modp = 0.f;
        for (int j = pjs; j < pje; ++j) {
            const int cl = clp[j];
            const float w = wp[j];
            const float4 sc4 = *(const float4*)(hbf + SL_OFF + cl * 20 + pkq * 4);
            g0 += w * sc4.x; g1 += w * sc4.y; g2 += w * sc4.z; g3 += w * sc4.w;
            const float d0 = sq.x - sc4.x, d1 = sq.y - sc4.y;
            const float d2 = sq.z - sc4.z, d3 = sq.w - sc4.w;
            modp += w * (d0*d0 + d1*d1 + d2*d2 + d3*d3);
        }
        float4 gv; gv.x = g0; gv.y = g1; gv.z = g2; gv.w = g3;
        *(float4*)(hbf + GL_OFF + pr * 20 + pkq * 4) = gv;
        #pragma unroll
        for (int off = 32; off; off >>= 1) modp += __shfl_down(modp, off);
        if (lane == 0) hbf[MRED_OFF + wave] = modp;
    }
    __syncthreads();   // [B8] G + mod partials visible
    if (t == 0) {
        float s = 0.f;
        #pragma unroll
        for (int w = 0; w < 16; ++w) s += hbf[MRED_OFF + w];
        modpart[bid] = s;
    }

    // Phase B: padj partials — thread (q=t>>8, k=(t>>4)&15, l=t&15) over rows [q*64,q*64+64)
    {
        const int q = t >> 8, kl = t & 255;
        const int k = kl >> 4, l = kl & 15;
        float acc = 0.f;
        const int r0 = q * 64;
        #pragma unroll 4
        for (int r = r0; r < r0 + 64; ++r)
            acc += hbf[SL_OFF + r * 20 + k] * hbf[GL_OFF + r * 20 + l];
        hbf[PJW_OFF + q * 256 + kl] = acc;
    }

    // Phase C: px partials — thread (rg=t>>8, kg=(t>>6)&3, f=t&63) over rows [rg*64,+64)
    {
        const int rg = t >> 8, kg = (t >> 6) & 3, f = t & 63;
        const float* xp = x_to_pool + (size_t)b * NN * (64 * DIMS) + f * DIMS + d;
        float xa0 = 0.f, xa1 = 0.f, xa2 = 0.f, xa3 = 0.f;
        const int n0 = rg * 64;
        #pragma unroll 4
        for (int n = n0; n < n0 + 64; ++n) {
            const float xv = xp[(size_t)n * (64 * DIMS)];
            const float4 s4 = *(const float4*)(hbf + SL_OFF + n * 20 + kg * 4);
            xa0 += xv * s4.x; xa1 += xv * s4.y; xa2 += xv * s4.z; xa3 += xv * s4.w;
        }
        float4 v; v.x = xa0; v.y = xa1; v.z = xa2; v.w = xa3;
        *(float4*)(hbf + PXP_OFF + ((rg * 4 + kg) * 64 + f) * 4) = v;
    }
    __syncthreads();   // [B9] padj + px partials visible

    // Phase D merges (deterministic fixed-order sums)
    if (t < 256) {     // pea: (k,l) = (t>>4, t&15)
        const float v = (hbf[PJW_OFF + t] + hbf[PJW_OFF + 256 + t]
                       + hbf[PJW_OFF + 512 + t] + hbf[PJW_OFF + 768 + t]) * (1.f / 256.f);
        out[PEA_OFF + (size_t)((b * KK + (t >> 4)) * KK + (t & 15)) * DIMS + d] = v;
    }
    {                  // px: (k,f) = (t>>6, t&63)
        const int k = t >> 6, f = t & 63;
        const int kg = k >> 2, e = k & 3;
        float s = 0.f;
        #pragma unroll
        for (int rg = 0; rg < 4; ++rg)
            s += hbf[PXP_OFF + ((rg * 4 + kg) * 64 + f) * 4 + e];
        out[PX_OFF + ((size_t)((b * KK + k) * 64) + f) * DIMS + d] = s * (1.f / 16.f);
    }
}

__global__ void aux_kernel(float* __restrict__ out)
{
    const int idx = blockIdx.x * 256 + threadIdx.x;
    if (idx < 2 * NTOT) {
        const int r = idx & (NTOT - 1);
        const int bb = r >> 8;
        const int j = r & 255;
        const int v = (idx < NTOT) ? (bb * KK + (j >> 4)) : (bb * KK + (j & 15));
        out[PEI_OFF + idx] = (float)v;
    } else if (idx < 2 * NTOT + NB * KK) {
        const int i = idx - 2 * NTOT;
        out[PB_OFF + i] = (float)(i >> 4);
    }
}

__global__ void loss_kernel(const float* __restrict__ entpart,
                            const float* __restrict__ modpart,
                            float* __restrict__ out)
{
    const int tid = threadIdx.x;
    float e = 0.f, m = 0.f;
    for (int i = tid; i < DIMS * NB; i += 256) { e += entpart[i]; m += modpart[i]; }
    #pragma unroll
    for (int off = 32; off; off >>= 1) { e += __shfl_down(e, off); m += __shfl_down(m, off); }
    __shared__ float er[4], mr[4];
    const int wave = tid >> 6, lane = tid & 63;
    if (lane == 0) { er[wave] = e; mr[wave] = m; }
    __syncthreads();
    if (tid == 0) {
        const float es = er[0] + er[1] + er[2] + er[3];
        const float ms = mr[0] + mr[1] + mr[2] + mr[3];
        out[LOSS_OFF] = ms / (float)NE + es / (float)(DIMS * NTOT);
    }
}

extern "C" void kernel_launch(void* const* d_in, const int* in_sizes, int n_in,
                              void* d_out, int out_size, void* d_ws, size_t ws_size,
                              hipStream_t stream)
{
    const float* x         = (const float*)d_in[0];
    const float* edge_attr = (const float*)d_in[1];
    const float* x_to_pool = (const float*)d_in[2];
    const float* Wm0 = (const float*)d_in[3];
    const float* Ws0 = (const float*)d_in[4];
    const float* b0  = (const float*)d_in[5];
    const float* Wm1 = (const float*)d_in[6];
    const float* Ws1 = (const float*)d_in[7];
    const float* b1  = (const float*)d_in[8];
    const float* Wm2 = (const float*)d_in[9];
    const float* Ws2 = (const float*)d_in[10];
    const float* b2  = (const float*)d_in[11];
    const float* fcW1= (const float*)d_in[12];
    const float* fcb1= (const float*)d_in[13];
    const float* fcW2= (const float*)d_in[14];
    const float* fcb2= (const float*)d_in[15];
    const int* edge_index = (const int*)d_in[16];
    float* out = (float*)d_out;
    char* ws = (char*)d_ws;
    float*         wrec  = (float*)(ws + WREC_WS);
    unsigned char* clrec = (unsigned char*)(ws + CLREC_WS);
    int*           iptr  = (int*)(ws + IPTR_WS);
    float*         entpart = (float*)(ws + ENT_WS);
    float*         modpart = (float*)(ws + MOD_WS);
    float*         wc    = (float*)(ws + WC_WS);
    float*         bc    = (float*)(ws + BC_WS);

    csr_build<<<dim3(NB), dim3(256), 0, stream>>>(edge_index, edge_attr, wrec, clrec, iptr);
    fc_combine<<<dim3(1), dim3(256), 0, stream>>>(fcW1, fcb1, fcW2, fcb2, wc, bc);
    gconv_kernel<<<dim3(DIMS * NB), dim3(1024), 0, stream>>>(
        x, x_to_pool, Wm0, Ws0, b0, Wm1, Ws1, b1, Wm2, Ws2, b2,
        wc, bc, wrec, clrec, iptr, out, entpart, modpart);
    aux_kernel<<<dim3((2 * NTOT + NB * KK + 255) / 256), dim3(256), 0, stream>>>(out);
    loss_kernel<<<dim3(1), dim3(256), 0, stream>>>(entpart, modpart, out);
}

// Round 18
// 565.955 us; speedup vs baseline: 1.0858x; 1.0170x over previous
//
#include <hip/hip_runtime.h>

#define DIMS 3
#define NB 256
#define NN 256
#define KK 16
#define HID 64
#define EPG 8192
#define NTOT (NB*NN)
#define NE (NB*EPG)

// d_out layout (flat concat of reference outputs, all as float)
#define PX_OFF   0          // (B*K, F, DIMS)           = 786432
#define PEI_OFF  786432     // (2, B*K*K)               = 131072
#define PEA_OFF  917504     // (B*K*K, DIMS)            = 196608
#define PB_OFF   1114112    // (B*K,)                   = 4096
#define LOSS_OFF 1118208    // scalar
#define S_OFF    1118209    // (DIMS, B, N, K)          = 3145728

// d_ws layout (bytes) — total ~27.5 MB
#define WREC_WS  0                 // float[3][NB*EPG] per-d edge weight (CSR order) = 24 MB
#define CLREC_WS 25165824          // uchar[NB*EPG] col-local index
#define IPTR_WS  27262976          // int[NB*257]
#define ENT_WS   27526144          // float[768]
#define MOD_WS   27529216          // float[768]
#define WC_WS    27532288          // float[144*16]  (fcW1 @ fcW2)
#define BC_WS    27541504          // float[16]      (fcb1 @ fcW2 + fcb2)

// LDS float-offsets inside hb (16384 floats) for the fused pool epilogue
#define SL_OFF   0         // s tile      [256][20]  -> [0, 5120)
#define GL_OFF   5120      // G tile      [256][20]  -> [5120, 10240)
#define PXP_OFF  10240     // px partials [16][64][4]-> [10240, 14336)
#define PJW_OFF  14336     // padj part.  [4][256]   -> [14336, 15360)
#define MRED_OFF 15360     // mod red     [16]
#define ERED_OFF 15380     // ent red     [16]

// ---------------- combined FC weights: Wc = fcW1@fcW2, bc = fcb1@fcW2+fcb2 ----------------
__global__ void fc_combine(const float* __restrict__ fcW1, const float* __restrict__ fcb1,
                           const float* __restrict__ fcW2, const float* __restrict__ fcb2,
                           float* __restrict__ wc, float* __restrict__ bc)
{
    const int t = threadIdx.x;
    for (int idx = t; idx < 144 * 16; idx += 256) {
        const int i = idx >> 4, k = idx & 15;
        float s = 0.f;
        for (int q = 0; q < 50; ++q) s += fcW1[i * 50 + q] * fcW2[q * 16 + k];
        wc[idx] = s;
    }
    if (t < 16) {
        float s = fcb2[t];
        for (int q = 0; q < 50; ++q) s += fcb1[q] * fcW2[q * 16 + t];
        bc[t] = s;
    }
}

// ------- CSR build: parallel deterministic counting sort (strided chunks) -------
#define HSTR 132
#define PSTR 129
__launch_bounds__(256)
__global__ void csr_build(const int* __restrict__ edge_index,
                          const float* __restrict__ edge_attr,
                          float* __restrict__ wrec, unsigned char* __restrict__ clrec,
                          int* __restrict__ indptr)
{
    __shared__ unsigned char  h[256 * HSTR];    // 33.8 KB
    __shared__ unsigned short po[256 * PSTR];   // 66.0 KB
    __shared__ int sc[256];
    const int b = blockIdx.x;
    const int t = threadIdx.x;
    const int* rowp = edge_index + (size_t)b * EPG;
    const int* colp = edge_index + (size_t)NB * EPG + (size_t)b * EPG;

    for (int i = t; i < 256 * HSTR / 4; i += 256) ((unsigned int*)h)[i] = 0u;
    __syncthreads();

    if (t < 128) {
        #pragma unroll 4
        for (int j = 0; j < 64; ++j) {
            const int r = rowp[t + 128 * j] & (NN - 1);
            h[r * HSTR + t]++;
        }
    }
    __syncthreads();

    int tot;
    {
        int s = 0;
        const unsigned int* hr = (const unsigned int*)(h + t * HSTR);
        #pragma unroll
        for (int c4 = 0; c4 < HSTR / 4; ++c4) {
            const unsigned int v = hr[c4];
            s += (v & 255) + ((v >> 8) & 255) + ((v >> 16) & 255) + (v >> 24);
        }
        tot = s;
        sc[t] = s;
    }
    __syncthreads();
    for (int ofs = 1; ofs < 256; ofs <<= 1) {
        int v = (t >= ofs) ? sc[t - ofs] : 0;
        __syncthreads();
        sc[t] += v;
        __syncthreads();
    }
    const int start = sc[t] - tot;
    indptr[b * 257 + t] = start;
    if (t == 255) indptr[b * 257 + 256] = EPG;

    {
        int run = start;
        #pragma unroll 4
        for (int c = 0; c < 128; ++c) {
            po[t * PSTR + c] = (unsigned short)run;
            run += h[t * HSTR + c];
        }
    }
    __syncthreads();

    if (t < 128) {
        const float* eap = edge_attr + (size_t)b * EPG * 3;
        float* w0 = wrec + (size_t)b * EPG;
        float* w1 = wrec + (size_t)NB * EPG + (size_t)b * EPG;
        float* w2 = wrec + 2 * (size_t)NB * EPG + (size_t)b * EPG;
        unsigned char* cdst = clrec + (size_t)b * EPG;
        #pragma unroll 2
        for (int j = 0; j < 64; ++j) {
            const int e = t + 128 * j;
            const int r = rowp[e] & (NN - 1);
            const int cl = colp[e] & (NN - 1);
            const int dest = po[r * PSTR + t]++;
            w0[dest] = eap[e * 3 + 0];
            w1[dest] = eap[e * 3 + 1];
            w2[dest] = eap[e * 3 + 2];
            cdst[dest] = (unsigned char)cl;
        }
    }
}

// -------- gconv v18 = v17 + FUSED DUAL-ROW GATHER: the two rows' edge streams are
// independent; interleaving them doubles in-flight ds_reads (2->4) for ~6 extra
// transient VGPRs (peak ~52 < 64 budget). Everything else identical to v17. --------
template<int OUTW, bool IS_L2>
__device__ __forceinline__ void layer_step(
    int rp, int o, int fr, int fkq, int js0, int je0, int je1,
    const float* __restrict__ wp, const unsigned char* __restrict__ clp,
    const float* __restrict__ Wm, const float* __restrict__ Ws,
    const float* __restrict__ bias, const float* __restrict__ wc, // wcomb + layer_row_off*16
    float4* hb4, float* p)
{
    constexpr int NCO = OUTW / 8;              // outputs/thread/row: 8 (L0/L1), 2 (L2)
    const int r0 = rp * 2, r1 = r0 + 1;
    const int b0 = r0 * 16, s0 = r0 & 15;
    const int b1 = r1 * 16, s1 = r1 & 15;
    const int c0 = o, c1 = o + 8;              // conflict-free chunk pair

    // P1: fused dual-row gather (independent chains -> 4 ds_reads in flight)
    float ga0[8], ga1[8];
    #pragma unroll
    for (int u = 0; u < 8; ++u) { ga0[u] = 0.f; ga1[u] = 0.f; }
    {
        const int n0 = je0 - js0, n1 = je1 - je0;
        const int nmin = (n0 < n1) ? n0 : n1;
        #pragma unroll 1
        for (int i = 0; i < nmin; ++i) {
            const int cla = clp[js0 + i];
            const int clb = clp[je0 + i];
            const float wa = wp[js0 + i];
            const float wb = wp[je0 + i];
            const int cba = cla * 16, csa = cla & 15;
            const int cbb = clb * 16, csb = clb & 15;
            const float4 a0 = hb4[cba + (c0 ^ csa)];
            const float4 a1 = hb4[cba + (c1 ^ csa)];
            const float4 bb0 = hb4[cbb + (c0 ^ csb)];
            const float4 bb1 = hb4[cbb + (c1 ^ csb)];
            ga0[0] += wa * a0.x; ga0[1] += wa * a0.y; ga0[2] += wa * a0.z; ga0[3] += wa * a0.w;
            ga0[4] += wa * a1.x; ga0[5] += wa * a1.y; ga0[6] += wa * a1.z; ga0[7] += wa * a1.w;
            ga1[0] += wb * bb0.x; ga1[1] += wb * bb0.y; ga1[2] += wb * bb0.z; ga1[3] += wb * bb0.w;
            ga1[4] += wb * bb1.x; ga1[5] += wb * bb1.y; ga1[6] += wb * bb1.z; ga1[7] += wb * bb1.w;
        }
        #pragma unroll 1
        for (int j = js0 + nmin; j < je0; ++j) {
            const int cl = clp[j];
            const float w = wp[j];
            const int cb = cl * 16, cs = cl & 15;
            const float4 ha = hb4[cb + (c0 ^ cs)];
            const float4 hb = hb4[cb + (c1 ^ cs)];
            ga0[0] += w * ha.x; ga0[1] += w * ha.y; ga0[2] += w * ha.z; ga0[3] += w * ha.w;
            ga0[4] += w * hb.x; ga0[5] += w * hb.y; ga0[6] += w * hb.z; ga0[7] += w * hb.w;
        }
        #pragma unroll 1
        for (int j = je0 + nmin; j < je1; ++j) {
            const int cl = clp[j];
            const float w = wp[j];
            const int cb = cl * 16, cs = cl & 15;
            const float4 ha = hb4[cb + (c0 ^ cs)];
            const float4 hb = hb4[cb + (c1 ^ cs)];
            ga1[0] += w * ha.x; ga1[1] += w * ha.y; ga1[2] += w * ha.z; ga1[3] += w * ha.w;
            ga1[4] += w * hb.x; ga1[5] += w * hb.y; ga1[6] += w * hb.z; ga1[7] += w * hb.w;
        }
    }

    // P2: acc = bias + h@Ws (single weight stream from global/L1)
    const int jA = o * 4;
    const int jB = o * 4 + 32;
    const int j0L2 = o * NCO;
    float acc0[NCO == 8 ? 8 : 2], acc1[NCO == 8 ? 8 : 2];
    if constexpr (NCO == 8) {
        const float4 bv0 = *(const float4*)(bias + jA);
        const float4 bv1 = *(const float4*)(bias + jB);
        acc0[0]=bv0.x; acc0[1]=bv0.y; acc0[2]=bv0.z; acc0[3]=bv0.w;
        acc0[4]=bv1.x; acc0[5]=bv1.y; acc0[6]=bv1.z; acc0[7]=bv1.w;
        #pragma unroll
        for (int u = 0; u < 8; ++u) acc1[u] = acc0[u];
    } else {
        acc0[0] = bias[j0L2]; acc0[1] = bias[j0L2 + 1];
        acc1[0] = acc0[0];    acc1[1] = acc0[1];
    }
    #pragma unroll 1
    for (int ic = 0; ic < 16; ++ic) {
        const float4 h40 = hb4[b0 + (ic ^ s0)];
        const float4 h41 = hb4[b1 + (ic ^ s1)];
        const float hv0[4] = {h40.x, h40.y, h40.z, h40.w};
        const float hv1[4] = {h41.x, h41.y, h41.z, h41.w};
        #pragma unroll
        for (int u = 0; u < 4; ++u) {
            const float* wr = Ws + (ic * 4 + u) * OUTW;
            const float a0 = hv0[u], a1 = hv1[u];
            if constexpr (NCO == 8) {
                const float4 wa = *(const float4*)(wr + jA);
                const float4 wb = *(const float4*)(wr + jB);
                acc0[0]+=a0*wa.x; acc0[1]+=a0*wa.y; acc0[2]+=a0*wa.z; acc0[3]+=a0*wa.w;
                acc0[4]+=a0*wb.x; acc0[5]+=a0*wb.y; acc0[6]+=a0*wb.z; acc0[7]+=a0*wb.w;
                acc1[0]+=a1*wa.x; acc1[1]+=a1*wa.y; acc1[2]+=a1*wa.z; acc1[3]+=a1*wa.w;
                acc1[4]+=a1*wb.x; acc1[5]+=a1*wb.y; acc1[6]+=a1*wb.z; acc1[7]+=a1*wb.w;
            } else {
                const float2 w2 = *(const float2*)(wr + j0L2);
                acc0[0]+=a0*w2.x; acc0[1]+=a0*w2.y;
                acc1[0]+=a1*w2.x; acc1[1]+=a1*w2.y;
            }
        }
    }
    __syncthreads();                           // [B1] all hb reads (gather + P2) done

    // P3: write agg over h
    {
        float4 v;
        v.x = ga0[0]; v.y = ga0[1]; v.z = ga0[2]; v.w = ga0[3]; hb4[b0 + (c0 ^ s0)] = v;
        v.x = ga0[4]; v.y = ga0[5]; v.z = ga0[6]; v.w = ga0[7]; hb4[b0 + (c1 ^ s0)] = v;
        v.x = ga1[0]; v.y = ga1[1]; v.z = ga1[2]; v.w = ga1[3]; hb4[b1 + (c0 ^ s1)] = v;
        v.x = ga1[4]; v.y = ga1[5]; v.z = ga1[6]; v.w = ga1[7]; hb4[b1 + (c1 ^ s1)] = v;
    }
    __syncthreads();                           // [B2] agg visible

    // P4: acc += agg@Wm
    #pragma unroll 1
    for (int ic = 0; ic < 16; ++ic) {
        const float4 a40 = hb4[b0 + (ic ^ s0)];
        const float4 a41 = hb4[b1 + (ic ^ s1)];
        const float av0[4] = {a40.x, a40.y, a40.z, a40.w};
        const float av1[4] = {a41.x, a41.y, a41.z, a41.w};
        #pragma unroll
        for (int u = 0; u < 4; ++u) {
            const float* wr = Wm + (ic * 4 + u) * OUTW;
            const float a0 = av0[u], a1 = av1[u];
            if constexpr (NCO == 8) {
                const float4 wa = *(const float4*)(wr + jA);
                const float4 wb = *(const float4*)(wr + jB);
                acc0[0]+=a0*wa.x; acc0[1]+=a0*wa.y; acc0[2]+=a0*wa.z; acc0[3]+=a0*wa.w;
                acc0[4]+=a0*wb.x; acc0[5]+=a0*wb.y; acc0[6]+=a0*wb.z; acc0[7]+=a0*wb.w;
                acc1[0]+=a1*wa.x; acc1[1]+=a1*wa.y; acc1[2]+=a1*wa.z; acc1[3]+=a1*wa.w;
                acc1[4]+=a1*wb.x; acc1[5]+=a1*wb.y; acc1[6]+=a1*wb.z; acc1[7]+=a1*wb.w;
            } else {
                const float2 w2 = *(const float2*)(wr + j0L2);
                acc0[0]+=a0*w2.x; acc0[1]+=a0*w2.y;
                acc1[0]+=a1*w2.x; acc1[1]+=a1*w2.y;
            }
        }
    }
    #pragma unroll
    for (int jj = 0; jj < NCO; ++jj) {
        acc0[jj] = fmaxf(acc0[jj], 0.f);
        acc1[jj] = fmaxf(acc1[jj], 0.f);
    }
    __syncthreads();                           // [B3] agg reads done

    // P5: write h_next
    if constexpr (!IS_L2) {
        float4 v;
        v.x = acc0[0]; v.y = acc0[1]; v.z = acc0[2]; v.w = acc0[3]; hb4[b0 + (c0 ^ s0)] = v;
        v.x = acc0[4]; v.y = acc0[5]; v.z = acc0[6]; v.w = acc0[7]; hb4[b0 + (c1 ^ s0)] = v;
        v.x = acc1[0]; v.y = acc1[1]; v.z = acc1[2]; v.w = acc1[3]; hb4[b1 + (c0 ^ s1)] = v;
        v.x = acc1[4]; v.y = acc1[5]; v.z = acc1[6]; v.w = acc1[7]; hb4[b1 + (c1 ^ s1)] = v;
    } else {
        float* hbf = (float*)hb4;
        const int cc = o >> 1, off = (o & 1) * 2;
        float* p0 = hbf + (b0 + (cc ^ s0)) * 4 + off;
        float* p1 = hbf + (b1 + (cc ^ s1)) * 4 + off;
        p0[0] = acc0[0]; p0[1] = acc0[1];
        p1[0] = acc1[0]; p1[1] = acc1[1];
    }
    __syncthreads();                           // [B4] h_next visible

    // FC: thread (fr,fkq) accumulates p[4] += h_next[fr][:] @ Wc[:, fkq*4..+4]
    {
        const int rb = fr * 16, rs = fr & 15;
        if constexpr (!IS_L2) {
            #pragma unroll 2
            for (int c4 = 0; c4 < 16; ++c4) {
                const float4 v4 = hb4[rb + (c4 ^ rs)];
                const float vv[4] = {v4.x, v4.y, v4.z, v4.w};
                #pragma unroll
                for (int e = 0; e < 4; ++e) {
                    const float4 w4 = *(const float4*)(wc + (c4 * 4 + e) * 16 + fkq * 4);
                    p[0] += vv[e] * w4.x; p[1] += vv[e] * w4.y;
                    p[2] += vv[e] * w4.z; p[3] += vv[e] * w4.w;
                }
            }
        } else {
            #pragma unroll 2
            for (int c4 = 0; c4 < 4; ++c4) {
                const float4 v4 = hb4[rb + (c4 ^ rs)];
                const float vv[4] = {v4.x, v4.y, v4.z, v4.w};
                #pragma unroll
                for (int e = 0; e < 4; ++e) {
                    const float4 w4 = *(const float4*)(wc + (c4 * 4 + e) * 16 + fkq * 4);
                    p[0] += vv[e] * w4.x; p[1] += vv[e] * w4.y;
                    p[2] += vv[e] * w4.z; p[3] += vv[e] * w4.w;
                }
            }
        }
    }
}

__launch_bounds__(1024)
__global__ void gconv_kernel(
    const float* __restrict__ x,
    const float* __restrict__ x_to_pool,
    const float* __restrict__ Wm0, const float* __restrict__ Ws0, const float* __restrict__ b0,
    const float* __restrict__ Wm1, const float* __restrict__ Ws1, const float* __restrict__ b1,
    const float* __restrict__ Wm2, const float* __restrict__ Ws2, const float* __restrict__ b2,
    const float* __restrict__ wcomb, const float* __restrict__ bcomb,
    const float* __restrict__ wrec, const unsigned char* __restrict__ clrec,
    const int* __restrict__ indptr,
    float* __restrict__ out, float* __restrict__ entpart, float* __restrict__ modpart)
{
    __shared__ float4 hb4[4096];       // exactly 64 KB — reused by the pool epilogue
    float* hbf = (float*)hb4;
    const int t = threadIdx.x;
    const int bid = blockIdx.x;
    const int d = bid >> 8;
    const int b = bid & (NB - 1);
    const int rp = t >> 3;         // row pair
    const int o = t & 7;           // chunk owner (chunks o, o+8)
    const int fr = t >> 2;         // FC row
    const int fkq = t & 3;         // FC k-quad
    const int lane = t & 63;
    const int wave = t >> 6;

    // stage x -> hb (swizzled)
    {
        const float4* xv = (const float4*)(x + (size_t)b * NN * HID);
        #pragma unroll
        for (int it = 0; it < 4; ++it) {
            const int idx = t + it * 1024;
            const int nrow = idx >> 4, c = idx & 15;
            hb4[nrow * 16 + (c ^ (nrow & 15))] = xv[idx];
        }
    }
    float p[4] = {0.f, 0.f, 0.f, 0.f};
    __syncthreads();   // [B0]

    const float* wp = wrec + (size_t)d * NB * EPG + (size_t)b * EPG;
    const unsigned char* clp = clrec + (size_t)b * EPG;
    const int* ipb = indptr + b * 257;
    const int js0 = ipb[rp * 2];
    const int je0 = ipb[rp * 2 + 1];
    const int je1 = ipb[rp * 2 + 2];

    layer_step<64, false>(rp, o, fr, fkq, js0, je0, je1, wp, clp, Wm0 + d*HID*HID,
                          Ws0 + d*HID*HID, b0 + d*HID, wcomb,          hb4, p);
    layer_step<64, false>(rp, o, fr, fkq, js0, je0, je1, wp, clp, Wm1 + d*HID*HID,
                          Ws1 + d*HID*HID, b1 + d*HID, wcomb + 64*16,  hb4, p);
    layer_step<16, true >(rp, o, fr, fkq, js0, je0, je1, wp, clp, Wm2 + d*HID*KK,
                          Ws2 + d*HID*KK,  b2 + d*KK,  wcomb + 128*16, hb4, p);

    __syncthreads();   // [B5] FC reads done — hb reusable
    {
        float* dst = hbf + SL_OFF + fr * 20 + fkq * 4;
        dst[0] = p[0]; dst[1] = p[1]; dst[2] = p[2]; dst[3] = p[3];
    }
    __syncthreads();   // [B6] logits visible

    // softmax + entropy (t<256); s overwrites logits region; s also -> out
    float ent_local = 0.f;
    if (t < 256) {
        const int rr = t;
        float* Lr = hbf + SL_OFF + rr * 20;
        float logits[KK];
        #pragma unroll
        for (int k = 0; k < KK; ++k) logits[k] = Lr[k] + bcomb[k];
        float m = logits[0];
        #pragma unroll
        for (int k = 1; k < KK; ++k) m = fmaxf(m, logits[k]);
        float sum = 0.f, sv[KK];
        #pragma unroll
        for (int k = 0; k < KK; ++k) { sv[k] = expf(logits[k] - m); sum += sv[k]; }
        const float inv = 1.f / sum;
        float4* sp4 = (float4*)(out + S_OFF + ((size_t)(d * NB + b) * NN + rr) * KK);
        #pragma unroll
        for (int q4 = 0; q4 < 4; ++q4) {
            float4 v;
            const float s0 = sv[q4*4+0] * inv, s1 = sv[q4*4+1] * inv;
            const float s2 = sv[q4*4+2] * inv, s3 = sv[q4*4+3] * inv;
            v.x = s0; v.y = s1; v.z = s2; v.w = s3;
            sp4[q4] = v;
            *(float4*)(Lr + q4 * 4) = v;          // s into LDS
            ent_local -= s0 * logf(s0 + 1e-15f) + s1 * logf(s1 + 1e-15f)
                       + s2 * logf(s2 + 1e-15f) + s3 * logf(s3 + 1e-15f);
        }
    }
    #pragma unroll
    for (int off = 32; off; off >>= 1) ent_local += __shfl_down(ent_local, off);
    if (lane == 0) hbf[ERED_OFF + wave] = ent_local;
    __syncthreads();   // [B7] s + ent partials visible
    if (t == 0) {
        float s = 0.f;
        #pragma unroll
        for (int w = 0; w < 16; ++w) s += hbf[ERED_OFF + w];
        entpart[bid] = s;
    }

    // ---- fused pool ----
    // Phase A: G = A*s (thread=(row pr, kquad pkq)) + modularity partial
    {
        const int pr = t >> 2, pkq = t & 3;
        const int pjs = ipb[pr], pje = ipb[pr + 1];
        const float4 sq = *(const float4*)(hbf + SL_OFF + pr * 20 + pkq * 4);
        float g0 = 0.f, g1 = 0.f, g2 = 0.f, g3 = 0.f;
        float modp = 0.f;
        for (int j = pjs; j < pje; ++j) {
            const int cl = clp[j];
            const float w = wp[j];
            const float4 sc4 = *(const float4*)(hbf + SL_OFF + cl * 20 + pkq * 4);
            g0 += w * sc4.x; g1 += w * sc4.y; g2 += w * sc4.z; g3 += w * sc4.w;
            const float d0 = sq.x - sc4.x, d1 = sq.y - sc4.y;
            const float d2 = sq.z - sc4.z, d3 = sq.w - sc4.w;
            modp += w * (d0*d0 + d1*d1 + d2*d2 + d3*d3);
        }
        float4 gv; gv.x = g0; gv.y = g1; gv.z = g2; gv.w = g3;
        *(float4*)(hbf + GL_OFF + pr * 20 + pkq * 4) = gv;
        #pragma unroll
        for (int off = 32; off; off >>= 1) modp += __shfl_down(modp, off);
        if (lane == 0) hbf[MRED_OFF + wave] = modp;
    }
    __syncthreads();   // [B8] G + mod partials visible
    if (t == 0) {
        float s = 0.f;
        #pragma unroll
        for (int w = 0; w < 16; ++w) s += hbf[MRED_OFF + w];
        modpart[bid] = s;
    }

    // Phase B: padj partials — thread (q=t>>8, k=(t>>4)&15, l=t&15) over rows [q*64,q*64+64)
    {
        const int q = t >> 8, kl = t & 255;
        const int k = kl >> 4, l = kl & 15;
        float acc = 0.f;
        const int r0 = q * 64;
        #pragma unroll 4
        for (int r = r0; r < r0 + 64; ++r)
            acc += hbf[SL_OFF + r * 20 + k] * hbf[GL_OFF + r * 20 + l];
        hbf[PJW_OFF + q * 256 + kl] = acc;
    }

    // Phase C: px partials — thread (rg=t>>8, kg=(t>>6)&3, f=t&63) over rows [rg*64,+64)
    {
        const int rg = t >> 8, kg = (t >> 6) & 3, f = t & 63;
        const float* xp = x_to_pool + (size_t)b * NN * (64 * DIMS) + f * DIMS + d;
        float xa0 = 0.f, xa1 = 0.f, xa2 = 0.f, xa3 = 0.f;
        const int n0 = rg * 64;
        #pragma unroll 4
        for (int n = n0; n < n0 + 64; ++n) {
            const float xv = xp[(size_t)n * (64 * DIMS)];
            const float4 s4 = *(const float4*)(hbf + SL_OFF + n * 20 + kg * 4);
            xa0 += xv * s4.x; xa1 += xv * s4.y; xa2 += xv * s4.z; xa3 += xv * s4.w;
        }
        float4 v; v.x = xa0; v.y = xa1; v.z = xa2; v.w = xa3;
        *(float4*)(hbf + PXP_OFF + ((rg * 4 + kg) * 64 + f) * 4) = v;
    }
    __syncthreads();   // [B9] padj + px partials visible

    // Phase D merges (deterministic fixed-order sums)
    if (t < 256) {     // pea: (k,l) = (t>>4, t&15)
        const float v = (hbf[PJW_OFF + t] + hbf[PJW_OFF + 256 + t]
                       + hbf[PJW_OFF + 512 + t] + hbf[PJW_OFF + 768 + t]) * (1.f / 256.f);
        out[PEA_OFF + (size_t)((b * KK + (t >> 4)) * KK + (t & 15)) * DIMS + d] = v;
    }
    {                  // px: (k,f) = (t>>6, t&63)
        const int k = t >> 6, f = t & 63;
        const int kg = k >> 2, e = k & 3;
        float s = 0.f;
        #pragma unroll
        for (int rg = 0; rg < 4; ++rg)
            s += hbf[PXP_OFF + ((rg * 4 + kg) * 64 + f) * 4 + e];
        out[PX_OFF + ((size_t)((b * KK + k) * 64) + f) * DIMS + d] = s * (1.f / 16.f);
    }
}

__global__ void aux_kernel(float* __restrict__ out)
{
    const int idx = blockIdx.x * 256 + threadIdx.x;
    if (idx < 2 * NTOT) {
        const int r = idx & (NTOT - 1);
        const int bb = r >> 8;
        const int j = r & 255;
        const int v = (idx < NTOT) ? (bb * KK + (j >> 4)) : (bb * KK + (j & 15));
        out[PEI_OFF + idx] = (float)v;
    } else if (idx < 2 * NTOT + NB * KK) {
        const int i = idx - 2 * NTOT;
        out[PB_OFF + i] = (float)(i >> 4);
    }
}

__global__ void loss_kernel(const float* __restrict__ entpart,
                            const float* __restrict__ modpart,
                            float* __restrict__ out)
{
    const int tid = threadIdx.x;
    float e = 0.f, m = 0.f;
    for (int i = tid; i < DIMS * NB; i += 256) { e += entpart[i]; m += modpart[i]; }
    #pragma unroll
    for (int off = 32; off; off >>= 1) { e += __shfl_down(e, off); m += __shfl_down(m, off); }
    __shared__ float er[4], mr[4];
    const int wave = tid >> 6, lane = tid & 63;
    if (lane == 0) { er[wave] = e; mr[wave] = m; }
    __syncthreads();
    if (tid == 0) {
        const float es = er[0] + er[1] + er[2] + er[3];
        const float ms = mr[0] + mr[1] + mr[2] + mr[3];
        out[LOSS_OFF] = ms / (float)NE + es / (float)(DIMS * NTOT);
    }
}

extern "C" void kernel_launch(void* const* d_in, const int* in_sizes, int n_in,
                              void* d_out, int out_size, void* d_ws, size_t ws_size,
                              hipStream_t stream)
{
    const float* x         = (const float*)d_in[0];
    const float* edge_attr = (const float*)d_in[1];
    const float* x_to_pool = (const float*)d_in[2];
    const float* Wm0 = (const float*)d_in[3];
    const float* Ws0 = (const float*)d_in[4];
    const float* b0  = (const float*)d_in[5];
    const float* Wm1 = (const float*)d_in[6];
    const float* Ws1 = (const float*)d_in[7];
    const float* b1  = (const float*)d_in[8];
    const float* Wm2 = (const float*)d_in[9];
    const float* Ws2 = (const float*)d_in[10];
    const float* b2  = (const float*)d_in[11];
    const float* fcW1= (const float*)d_in[12];
    const float* fcb1= (const float*)d_in[13];
    const float* fcW2= (const float*)d_in[14];
    const float* fcb2= (const float*)d_in[15];
    const int* edge_index = (const int*)d_in[16];
    float* out = (float*)d_out;
    char* ws = (char*)d_ws;
    float*         wrec  = (float*)(ws + WREC_WS);
    unsigned char* clrec = (unsigned char*)(ws + CLREC_WS);
    int*           iptr  = (int*)(ws + IPTR_WS);
    float*         entpart = (float*)(ws + ENT_WS);
    float*         modpart = (float*)(ws + MOD_WS);
    float*         wc    = (float*)(ws + WC_WS);
    float*         bc    = (float*)(ws + BC_WS);

    csr_build<<<dim3(NB), dim3(256), 0, stream>>>(edge_index, edge_attr, wrec, clrec, iptr);
    fc_combine<<<dim3(1), dim3(256), 0, stream>>>(fcW1, fcb1, fcW2, fcb2, wc, bc);
    gconv_kernel<<<dim3(DIMS * NB), dim3(1024), 0, stream>>>(
        x, x_to_pool, Wm0, Ws0, b0, Wm1, Ws1, b1, Wm2, Ws2, b2,
        wc, bc, wrec, clrec, iptr, out, entpart, modpart);
    aux_kernel<<<dim3((2 * NTOT + NB * KK + 255) / 256), dim3(256), 0, stream>>>(out);
    loss_kernel<<<dim3(1), dim3(256), 0, stream>>>(entpart, modpart, out);
}

// Round 19
// 562.486 us; speedup vs baseline: 1.0925x; 1.0062x over previous
//
#include <hip/hip_runtime.h>

#define DIMS 3
#define NB 256
#define NN 256
#define KK 16
#define HID 64
#define EPG 8192
#define NTOT (NB*NN)
#define NE (NB*EPG)

// d_out layout (flat concat of reference outputs, all as float)
#define PX_OFF   0          // (B*K, F, DIMS)           = 786432
#define PEI_OFF  786432     // (2, B*K*K)               = 131072
#define PEA_OFF  917504     // (B*K*K, DIMS)            = 196608
#define PB_OFF   1114112    // (B*K,)                   = 4096
#define LOSS_OFF 1118208    // scalar
#define S_OFF    1118209    // (DIMS, B, N, K)          = 3145728

// d_ws layout (bytes) — total ~27.5 MB
#define WREC_WS  0                 // float[3][NB*EPG] per-d edge weight (CSR order) = 24 MB
#define CLREC_WS 25165824          // uchar[NB*EPG] col-local index
#define IPTR_WS  27262976          // int[NB*257]
#define ENT_WS   27526144          // float[768]
#define MOD_WS   27529216          // float[768]
#define WC_WS    27532288          // float[144*16]  (fcW1 @ fcW2)
#define BC_WS    27541504          // float[16]      (fcb1 @ fcW2 + fcb2)

// LDS float-offsets inside hb (16384 floats) for the fused pool epilogue
#define SL_OFF   0         // s tile      [256][20]  -> [0, 5120)
#define GL_OFF   5120      // G tile      [256][20]  -> [5120, 10240)
#define PXP_OFF  10240     // px partials [16][64][4]-> [10240, 14336)
#define PJW_OFF  14336     // padj part.  [4][256]   -> [14336, 15360)
#define MRED_OFF 15360     // mod red     [16]
#define ERED_OFF 15380     // ent red     [16]

// ---------------- combined FC weights: Wc = fcW1@fcW2, bc = fcb1@fcW2+fcb2 ----------------
__global__ void fc_combine(const float* __restrict__ fcW1, const float* __restrict__ fcb1,
                           const float* __restrict__ fcW2, const float* __restrict__ fcb2,
                           float* __restrict__ wc, float* __restrict__ bc)
{
    const int t = threadIdx.x;
    for (int idx = t; idx < 144 * 16; idx += 256) {
        const int i = idx >> 4, k = idx & 15;
        float s = 0.f;
        for (int q = 0; q < 50; ++q) s += fcW1[i * 50 + q] * fcW2[q * 16 + k];
        wc[idx] = s;
    }
    if (t < 16) {
        float s = fcb2[t];
        for (int q = 0; q < 50; ++q) s += fcb1[q] * fcW2[q * 16 + t];
        bc[t] = s;
    }
}

// ------- CSR build: parallel deterministic counting sort (strided chunks) -------
#define HSTR 132
#define PSTR 129
__launch_bounds__(256)
__global__ void csr_build(const int* __restrict__ edge_index,
                          const float* __restrict__ edge_attr,
                          float* __restrict__ wrec, unsigned char* __restrict__ clrec,
                          int* __restrict__ indptr)
{
    __shared__ unsigned char  h[256 * HSTR];    // 33.8 KB
    __shared__ unsigned short po[256 * PSTR];   // 66.0 KB
    __shared__ int sc[256];
    const int b = blockIdx.x;
    const int t = threadIdx.x;
    const int* rowp = edge_index + (size_t)b * EPG;
    const int* colp = edge_index + (size_t)NB * EPG + (size_t)b * EPG;

    for (int i = t; i < 256 * HSTR / 4; i += 256) ((unsigned int*)h)[i] = 0u;
    __syncthreads();

    if (t < 128) {
        #pragma unroll 4
        for (int j = 0; j < 64; ++j) {
            const int r = rowp[t + 128 * j] & (NN - 1);
            h[r * HSTR + t]++;
        }
    }
    __syncthreads();

    int tot;
    {
        int s = 0;
        const unsigned int* hr = (const unsigned int*)(h + t * HSTR);
        #pragma unroll
        for (int c4 = 0; c4 < HSTR / 4; ++c4) {
            const unsigned int v = hr[c4];
            s += (v & 255) + ((v >> 8) & 255) + ((v >> 16) & 255) + (v >> 24);
        }
        tot = s;
        sc[t] = s;
    }
    __syncthreads();
    for (int ofs = 1; ofs < 256; ofs <<= 1) {
        int v = (t >= ofs) ? sc[t - ofs] : 0;
        __syncthreads();
        sc[t] += v;
        __syncthreads();
    }
    const int start = sc[t] - tot;
    indptr[b * 257 + t] = start;
    if (t == 255) indptr[b * 257 + 256] = EPG;

    {
        int run = start;
        #pragma unroll 4
        for (int c = 0; c < 128; ++c) {
            po[t * PSTR + c] = (unsigned short)run;
            run += h[t * HSTR + c];
        }
    }
    __syncthreads();

    if (t < 128) {
        const float* eap = edge_attr + (size_t)b * EPG * 3;
        float* w0 = wrec + (size_t)b * EPG;
        float* w1 = wrec + (size_t)NB * EPG + (size_t)b * EPG;
        float* w2 = wrec + 2 * (size_t)NB * EPG + (size_t)b * EPG;
        unsigned char* cdst = clrec + (size_t)b * EPG;
        #pragma unroll 2
        for (int j = 0; j < 64; ++j) {
            const int e = t + 128 * j;
            const int r = rowp[e] & (NN - 1);
            const int cl = colp[e] & (NN - 1);
            const int dest = po[r * PSTR + t]++;
            w0[dest] = eap[e * 3 + 0];
            w1[dest] = eap[e * 3 + 1];
            w2[dest] = eap[e * 3 + 2];
            cdst[dest] = (unsigned char)cl;
        }
    }
}

// -------- gconv v19 = v18 + VGPR budget raised to 112 (4 waves/SIMD is pinned anyway;
// 4x112=448<512) and the freed registers spent on ILP: gather unrolled x2 over edges
// (8 ds_reads in flight) and pool Phase A unrolled x2. --------
template<int OUTW, bool IS_L2>
__device__ __forceinline__ void layer_step(
    int rp, int o, int fr, int fkq, int js0, int je0, int je1,
    const float* __restrict__ wp, const unsigned char* __restrict__ clp,
    const float* __restrict__ Wm, const float* __restrict__ Ws,
    const float* __restrict__ bias, const float* __restrict__ wc, // wcomb + layer_row_off*16
    float4* hb4, float* p)
{
    constexpr int NCO = OUTW / 8;              // outputs/thread/row: 8 (L0/L1), 2 (L2)
    const int r0 = rp * 2, r1 = r0 + 1;
    const int b0 = r0 * 16, s0 = r0 & 15;
    const int b1 = r1 * 16, s1 = r1 & 15;
    const int c0 = o, c1 = o + 8;              // conflict-free chunk pair

    // P1: fused dual-row gather, unrolled x2 (up to 8 ds_reads in flight)
    float ga0[8], ga1[8];
    #pragma unroll
    for (int u = 0; u < 8; ++u) { ga0[u] = 0.f; ga1[u] = 0.f; }
    {
        const int n0 = je0 - js0, n1 = je1 - je0;
        const int nmin = (n0 < n1) ? n0 : n1;
        int i = 0;
        #pragma unroll 1
        for (; i + 2 <= nmin; i += 2) {
            const int cla0 = clp[js0 + i],     clb0 = clp[je0 + i];
            const int cla1 = clp[js0 + i + 1], clb1 = clp[je0 + i + 1];
            const float wa0 = wp[js0 + i],     wb0 = wp[je0 + i];
            const float wa1 = wp[js0 + i + 1], wb1 = wp[je0 + i + 1];
            const int ba0 = cla0 * 16, sa0 = cla0 & 15;
            const int bb0 = clb0 * 16, sb0 = clb0 & 15;
            const int ba1 = cla1 * 16, sa1 = cla1 & 15;
            const int bb1 = clb1 * 16, sb1 = clb1 & 15;
            const float4 xa00 = hb4[ba0 + (c0 ^ sa0)];
            const float4 xa01 = hb4[ba0 + (c1 ^ sa0)];
            const float4 xb00 = hb4[bb0 + (c0 ^ sb0)];
            const float4 xb01 = hb4[bb0 + (c1 ^ sb0)];
            const float4 xa10 = hb4[ba1 + (c0 ^ sa1)];
            const float4 xa11 = hb4[ba1 + (c1 ^ sa1)];
            const float4 xb10 = hb4[bb1 + (c0 ^ sb1)];
            const float4 xb11 = hb4[bb1 + (c1 ^ sb1)];
            ga0[0] += wa0 * xa00.x + wa1 * xa10.x;
            ga0[1] += wa0 * xa00.y + wa1 * xa10.y;
            ga0[2] += wa0 * xa00.z + wa1 * xa10.z;
            ga0[3] += wa0 * xa00.w + wa1 * xa10.w;
            ga0[4] += wa0 * xa01.x + wa1 * xa11.x;
            ga0[5] += wa0 * xa01.y + wa1 * xa11.y;
            ga0[6] += wa0 * xa01.z + wa1 * xa11.z;
            ga0[7] += wa0 * xa01.w + wa1 * xa11.w;
            ga1[0] += wb0 * xb00.x + wb1 * xb10.x;
            ga1[1] += wb0 * xb00.y + wb1 * xb10.y;
            ga1[2] += wb0 * xb00.z + wb1 * xb10.z;
            ga1[3] += wb0 * xb00.w + wb1 * xb10.w;
            ga1[4] += wb0 * xb01.x + wb1 * xb11.x;
            ga1[5] += wb0 * xb01.y + wb1 * xb11.y;
            ga1[6] += wb0 * xb01.z + wb1 * xb11.z;
            ga1[7] += wb0 * xb01.w + wb1 * xb11.w;
        }
        #pragma unroll 1
        for (; i < nmin; ++i) {
            const int cla = clp[js0 + i];
            const int clb = clp[je0 + i];
            const float wa = wp[js0 + i];
            const float wb = wp[je0 + i];
            const int cba = cla * 16, csa = cla & 15;
            const int cbb = clb * 16, csb = clb & 15;
            const float4 a0 = hb4[cba + (c0 ^ csa)];
            const float4 a1 = hb4[cba + (c1 ^ csa)];
            const float4 bb0 = hb4[cbb + (c0 ^ csb)];
            const float4 bb1 = hb4[cbb + (c1 ^ csb)];
            ga0[0] += wa * a0.x; ga0[1] += wa * a0.y; ga0[2] += wa * a0.z; ga0[3] += wa * a0.w;
            ga0[4] += wa * a1.x; ga0[5] += wa * a1.y; ga0[6] += wa * a1.z; ga0[7] += wa * a1.w;
            ga1[0] += wb * bb0.x; ga1[1] += wb * bb0.y; ga1[2] += wb * bb0.z; ga1[3] += wb * bb0.w;
            ga1[4] += wb * bb1.x; ga1[5] += wb * bb1.y; ga1[6] += wb * bb1.z; ga1[7] += wb * bb1.w;
        }
        #pragma unroll 1
        for (int j = js0 + nmin; j < je0; ++j) {
            const int cl = clp[j];
            const float w = wp[j];
            const int cb = cl * 16, cs = cl & 15;
            const float4 ha = hb4[cb + (c0 ^ cs)];
            const float4 hb = hb4[cb + (c1 ^ cs)];
            ga0[0] += w * ha.x; ga0[1] += w * ha.y; ga0[2] += w * ha.z; ga0[3] += w * ha.w;
            ga0[4] += w * hb.x; ga0[5] += w * hb.y; ga0[6] += w * hb.z; ga0[7] += w * hb.w;
        }
        #pragma unroll 1
        for (int j = je0 + nmin; j < je1; ++j) {
            const int cl = clp[j];
            const float w = wp[j];
            const int cb = cl * 16, cs = cl & 15;
            const float4 ha = hb4[cb + (c0 ^ cs)];
            const float4 hb = hb4[cb + (c1 ^ cs)];
            ga1[0] += w * ha.x; ga1[1] += w * ha.y; ga1[2] += w * ha.z; ga1[3] += w * ha.w;
            ga1[4] += w * hb.x; ga1[5] += w * hb.y; ga1[6] += w * hb.z; ga1[7] += w * hb.w;
        }
    }

    // P2: acc = bias + h@Ws (single weight stream from global/L1)
    const int jA = o * 4;
    const int jB = o * 4 + 32;
    const int j0L2 = o * NCO;
    float acc0[NCO == 8 ? 8 : 2], acc1[NCO == 8 ? 8 : 2];
    if constexpr (NCO == 8) {
        const float4 bv0 = *(const float4*)(bias + jA);
        const float4 bv1 = *(const float4*)(bias + jB);
        acc0[0]=bv0.x; acc0[1]=bv0.y; acc0[2]=bv0.z; acc0[3]=bv0.w;
        acc0[4]=bv1.x; acc0[5]=bv1.y; acc0[6]=bv1.z; acc0[7]=bv1.w;
        #pragma unroll
        for (int u = 0; u < 8; ++u) acc1[u] = acc0[u];
    } else {
        acc0[0] = bias[j0L2]; acc0[1] = bias[j0L2 + 1];
        acc1[0] = acc0[0];    acc1[1] = acc0[1];
    }
    #pragma unroll 1
    for (int ic = 0; ic < 16; ++ic) {
        const float4 h40 = hb4[b0 + (ic ^ s0)];
        const float4 h41 = hb4[b1 + (ic ^ s1)];
        const float hv0[4] = {h40.x, h40.y, h40.z, h40.w};
        const float hv1[4] = {h41.x, h41.y, h41.z, h41.w};
        #pragma unroll
        for (int u = 0; u < 4; ++u) {
            const float* wr = Ws + (ic * 4 + u) * OUTW;
            const float a0 = hv0[u], a1 = hv1[u];
            if constexpr (NCO == 8) {
                const float4 wa = *(const float4*)(wr + jA);
                const float4 wb = *(const float4*)(wr + jB);
                acc0[0]+=a0*wa.x; acc0[1]+=a0*wa.y; acc0[2]+=a0*wa.z; acc0[3]+=a0*wa.w;
                acc0[4]+=a0*wb.x; acc0[5]+=a0*wb.y; acc0[6]+=a0*wb.z; acc0[7]+=a0*wb.w;
                acc1[0]+=a1*wa.x; acc1[1]+=a1*wa.y; acc1[2]+=a1*wa.z; acc1[3]+=a1*wa.w;
                acc1[4]+=a1*wb.x; acc1[5]+=a1*wb.y; acc1[6]+=a1*wb.z; acc1[7]+=a1*wb.w;
            } else {
                const float2 w2 = *(const float2*)(wr + j0L2);
                acc0[0]+=a0*w2.x; acc0[1]+=a0*w2.y;
                acc1[0]+=a1*w2.x; acc1[1]+=a1*w2.y;
            }
        }
    }
    __syncthreads();                           // [B1] all hb reads (gather + P2) done

    // P3: write agg over h
    {
        float4 v;
        v.x = ga0[0]; v.y = ga0[1]; v.z = ga0[2]; v.w = ga0[3]; hb4[b0 + (c0 ^ s0)] = v;
        v.x = ga0[4]; v.y = ga0[5]; v.z = ga0[6]; v.w = ga0[7]; hb4[b0 + (c1 ^ s0)] = v;
        v.x = ga1[0]; v.y = ga1[1]; v.z = ga1[2]; v.w = ga1[3]; hb4[b1 + (c0 ^ s1)] = v;
        v.x = ga1[4]; v.y = ga1[5]; v.z = ga1[6]; v.w = ga1[7]; hb4[b1 + (c1 ^ s1)] = v;
    }
    __syncthreads();                           // [B2] agg visible

    // P4: acc += agg@Wm
    #pragma unroll 1
    for (int ic = 0; ic < 16; ++ic) {
        const float4 a40 = hb4[b0 + (ic ^ s0)];
        const float4 a41 = hb4[b1 + (ic ^ s1)];
        const float av0[4] = {a40.x, a40.y, a40.z, a40.w};
        const float av1[4] = {a41.x, a41.y, a41.z, a41.w};
        #pragma unroll
        for (int u = 0; u < 4; ++u) {
            const float* wr = Wm + (ic * 4 + u) * OUTW;
            const float a0 = av0[u], a1 = av1[u];
            if constexpr (NCO == 8) {
                const float4 wa = *(const float4*)(wr + jA);
                const float4 wb = *(const float4*)(wr + jB);
                acc0[0]+=a0*wa.x; acc0[1]+=a0*wa.y; acc0[2]+=a0*wa.z; acc0[3]+=a0*wa.w;
                acc0[4]+=a0*wb.x; acc0[5]+=a0*wb.y; acc0[6]+=a0*wb.z; acc0[7]+=a0*wb.w;
                acc1[0]+=a1*wa.x; acc1[1]+=a1*wa.y; acc1[2]+=a1*wa.z; acc1[3]+=a1*wa.w;
                acc1[4]+=a1*wb.x; acc1[5]+=a1*wb.y; acc1[6]+=a1*wb.z; acc1[7]+=a1*wb.w;
            } else {
                const float2 w2 = *(const float2*)(wr + j0L2);
                acc0[0]+=a0*w2.x; acc0[1]+=a0*w2.y;
                acc1[0]+=a1*w2.x; acc1[1]+=a1*w2.y;
            }
        }
    }
    #pragma unroll
    for (int jj = 0; jj < NCO; ++jj) {
        acc0[jj] = fmaxf(acc0[jj], 0.f);
        acc1[jj] = fmaxf(acc1[jj], 0.f);
    }
    __syncthreads();                           // [B3] agg reads done

    // P5: write h_next
    if constexpr (!IS_L2) {
        float4 v;
        v.x = acc0[0]; v.y = acc0[1]; v.z = acc0[2]; v.w = acc0[3]; hb4[b0 + (c0 ^ s0)] = v;
        v.x = acc0[4]; v.y = acc0[5]; v.z = acc0[6]; v.w = acc0[7]; hb4[b0 + (c1 ^ s0)] = v;
        v.x = acc1[0]; v.y = acc1[1]; v.z = acc1[2]; v.w = acc1[3]; hb4[b1 + (c0 ^ s1)] = v;
        v.x = acc1[4]; v.y = acc1[5]; v.z = acc1[6]; v.w = acc1[7]; hb4[b1 + (c1 ^ s1)] = v;
    } else {
        float* hbf = (float*)hb4;
        const int cc = o >> 1, off = (o & 1) * 2;
        float* p0 = hbf + (b0 + (cc ^ s0)) * 4 + off;
        float* p1 = hbf + (b1 + (cc ^ s1)) * 4 + off;
        p0[0] = acc0[0]; p0[1] = acc0[1];
        p1[0] = acc1[0]; p1[1] = acc1[1];
    }
    __syncthreads();                           // [B4] h_next visible

    // FC: thread (fr,fkq) accumulates p[4] += h_next[fr][:] @ Wc[:, fkq*4..+4]
    {
        const int rb = fr * 16, rs = fr & 15;
        if constexpr (!IS_L2) {
            #pragma unroll 2
            for (int c4 = 0; c4 < 16; ++c4) {
                const float4 v4 = hb4[rb + (c4 ^ rs)];
                const float vv[4] = {v4.x, v4.y, v4.z, v4.w};
                #pragma unroll
                for (int e = 0; e < 4; ++e) {
                    const float4 w4 = *(const float4*)(wc + (c4 * 4 + e) * 16 + fkq * 4);
                    p[0] += vv[e] * w4.x; p[1] += vv[e] * w4.y;
                    p[2] += vv[e] * w4.z; p[3] += vv[e] * w4.w;
                }
            }
        } else {
            #pragma unroll 2
            for (int c4 = 0; c4 < 4; ++c4) {
                const float4 v4 = hb4[rb + (c4 ^ rs)];
                const float vv[4] = {v4.x, v4.y, v4.z, v4.w};
                #pragma unroll
                for (int e = 0; e < 4; ++e) {
                    const float4 w4 = *(const float4*)(wc + (c4 * 4 + e) * 16 + fkq * 4);
                    p[0] += vv[e] * w4.x; p[1] += vv[e] * w4.y;
                    p[2] += vv[e] * w4.z; p[3] += vv[e] * w4.w;
                }
            }
        }
    }
}

__launch_bounds__(1024)
__attribute__((amdgpu_num_vgpr(112)))   // 4 waves/SIMD x 112 = 448 < 512; ILP headroom
__global__ void gconv_kernel(
    const float* __restrict__ x,
    const float* __restrict__ x_to_pool,
    const float* __restrict__ Wm0, const float* __restrict__ Ws0, const float* __restrict__ b0,
    const float* __restrict__ Wm1, const float* __restrict__ Ws1, const float* __restrict__ b1,
    const float* __restrict__ Wm2, const float* __restrict__ Ws2, const float* __restrict__ b2,
    const float* __restrict__ wcomb, const float* __restrict__ bcomb,
    const float* __restrict__ wrec, const unsigned char* __restrict__ clrec,
    const int* __restrict__ indptr,
    float* __restrict__ out, float* __restrict__ entpart, float* __restrict__ modpart)
{
    __shared__ float4 hb4[4096];       // exactly 64 KB — reused by the pool epilogue
    float* hbf = (float*)hb4;
    const int t = threadIdx.x;
    const int bid = blockIdx.x;
    const int d = bid >> 8;
    const int b = bid & (NB - 1);
    const int rp = t >> 3;         // row pair
    const int o = t & 7;           // chunk owner (chunks o, o+8)
    const int fr = t >> 2;         // FC row
    const int fkq = t & 3;         // FC k-quad
    const int lane = t & 63;
    const int wave = t >> 6;

    // stage x -> hb (swizzled)
    {
        const float4* xv = (const float4*)(x + (size_t)b * NN * HID);
        #pragma unroll
        for (int it = 0; it < 4; ++it) {
            const int idx = t + it * 1024;
            const int nrow = idx >> 4, c = idx & 15;
            hb4[nrow * 16 + (c ^ (nrow & 15))] = xv[idx];
        }
    }
    float p[4] = {0.f, 0.f, 0.f, 0.f};
    __syncthreads();   // [B0]

    const float* wp = wrec + (size_t)d * NB * EPG + (size_t)b * EPG;
    const unsigned char* clp = clrec + (size_t)b * EPG;
    const int* ipb = indptr + b * 257;
    const int js0 = ipb[rp * 2];
    const int je0 = ipb[rp * 2 + 1];
    const int je1 = ipb[rp * 2 + 2];

    layer_step<64, false>(rp, o, fr, fkq, js0, je0, je1, wp, clp, Wm0 + d*HID*HID,
                          Ws0 + d*HID*HID, b0 + d*HID, wcomb,          hb4, p);
    layer_step<64, false>(rp, o, fr, fkq, js0, je0, je1, wp, clp, Wm1 + d*HID*HID,
                          Ws1 + d*HID*HID, b1 + d*HID, wcomb + 64*16,  hb4, p);
    layer_step<16, true >(rp, o, fr, fkq, js0, je0, je1, wp, clp, Wm2 + d*HID*KK,
                          Ws2 + d*HID*KK,  b2 + d*KK,  wcomb + 128*16, hb4, p);

    __syncthreads();   // [B5] FC reads done — hb reusable
    {
        float* dst = hbf + SL_OFF + fr * 20 + fkq * 4;
        dst[0] = p[0]; dst[1] = p[1]; dst[2] = p[2]; dst[3] = p[3];
    }
    __syncthreads();   // [B6] logits visible

    // softmax + entropy (t<256); s overwrites logits region; s also -> out
    float ent_local = 0.f;
    if (t < 256) {
        const int rr = t;
        float* Lr = hbf + SL_OFF + rr * 20;
        float logits[KK];
        #pragma unroll
        for (int k = 0; k < KK; ++k) logits[k] = Lr[k] + bcomb[k];
        float m = logits[0];
        #pragma unroll
        for (int k = 1; k < KK; ++k) m = fmaxf(m, logits[k]);
        float sum = 0.f, sv[KK];
        #pragma unroll
        for (int k = 0; k < KK; ++k) { sv[k] = expf(logits[k] - m); sum += sv[k]; }
        const float inv = 1.f / sum;
        float4* sp4 = (float4*)(out + S_OFF + ((size_t)(d * NB + b) * NN + rr) * KK);
        #pragma unroll
        for (int q4 = 0; q4 < 4; ++q4) {
            float4 v;
            const float s0 = sv[q4*4+0] * inv, s1 = sv[q4*4+1] * inv;
            const float s2 = sv[q4*4+2] * inv, s3 = sv[q4*4+3] * inv;
            v.x = s0; v.y = s1; v.z = s2; v.w = s3;
            sp4[q4] = v;
            *(float4*)(Lr + q4 * 4) = v;          // s into LDS
            ent_local -= s0 * logf(s0 + 1e-15f) + s1 * logf(s1 + 1e-15f)
                       + s2 * logf(s2 + 1e-15f) + s3 * logf(s3 + 1e-15f);
        }
    }
    #pragma unroll
    for (int off = 32; off; off >>= 1) ent_local += __shfl_down(ent_local, off);
    if (lane == 0) hbf[ERED_OFF + wave] = ent_local;
    __syncthreads();   // [B7] s + ent partials visible
    if (t == 0) {
        float s = 0.f;
        #pragma unroll
        for (int w = 0; w < 16; ++w) s += hbf[ERED_OFF + w];
        entpart[bid] = s;
    }

    // ---- fused pool ----
    // Phase A: G = A*s (thread=(row pr, kquad pkq)) + modularity partial, unrolled x2
    {
        const int pr = t >> 2, pkq = t & 3;
        const int pjs = ipb[pr], pje = ipb[pr + 1];
        const float4 sq = *(const float4*)(hbf + SL_OFF + pr * 20 + pkq * 4);
        float g0 = 0.f, g1 = 0.f, g2 = 0.f, g3 = 0.f;
        float modp = 0.f;
        int j = pjs;
        #pragma unroll 1
        for (; j + 2 <= pje; j += 2) {
            const int cl0 = clp[j], cl1 = clp[j + 1];
            const float w0 = wp[j], w1 = wp[j + 1];
            const float4 sa = *(const float4*)(hbf + SL_OFF + cl0 * 20 + pkq * 4);
            const float4 sb = *(const float4*)(hbf + SL_OFF + cl1 * 20 + pkq * 4);
            g0 += w0 * sa.x + w1 * sb.x; g1 += w0 * sa.y + w1 * sb.y;
            g2 += w0 * sa.z + w1 * sb.z; g3 += w0 * sa.w + w1 * sb.w;
            const float a0 = sq.x - sa.x, a1 = sq.y - sa.y, a2 = sq.z - sa.z, a3 = sq.w - sa.w;
            const float b0v = sq.x - sb.x, b1v = sq.y - sb.y, b2v = sq.z - sb.z, b3v = sq.w - sb.w;
            modp += w0 * (a0*a0 + a1*a1 + a2*a2 + a3*a3)
                  + w1 * (b0v*b0v + b1v*b1v + b2v*b2v + b3v*b3v);
        }
        if (j < pje) {
            const int cl = clp[j];
            const float w = wp[j];
            const float4 sc4 = *(const float4*)(hbf + SL_OFF + cl * 20 + pkq * 4);
            g0 += w * sc4.x; g1 += w * sc4.y; g2 += w * sc4.z; g3 += w * sc4.w;
            const float d0 = sq.x - sc4.x, d1 = sq.y - sc4.y;
            const float d2 = sq.z - sc4.z, d3 = sq.w - sc4.w;
            modp += w * (d0*d0 + d1*d1 + d2*d2 + d3*d3);
        }
        float4 gv; gv.x = g0; gv.y = g1; gv.z = g2; gv.w = g3;
        *(float4*)(hbf + GL_OFF + pr * 20 + pkq * 4) = gv;
        #pragma unroll
        for (int off = 32; off; off >>= 1) modp += __shfl_down(modp, off);
        if (lane == 0) hbf[MRED_OFF + wave] = modp;
    }
    __syncthreads();   // [B8] G + mod partials visible
    if (t == 0) {
        float s = 0.f;
        #pragma unroll
        for (int w = 0; w < 16; ++w) s += hbf[MRED_OFF + w];
        modpart[bid] = s;
    }

    // Phase B: padj partials — thread (q=t>>8, k=(t>>4)&15, l=t&15) over rows [q*64,q*64+64)
    {
        const int q = t >> 8, kl = t & 255;
        const int k = kl >> 4, l = kl & 15;
        float acc = 0.f;
        const int r0 = q * 64;
        #pragma unroll 4
        for (int r = r0; r < r0 + 64; ++r)
            acc += hbf[SL_OFF + r * 20 + k] * hbf[GL_OFF + r * 20 + l];
        hbf[PJW_OFF + q * 256 + kl] = acc;
    }

    // Phase C: px partials — thread (rg=t>>8, kg=(t>>6)&3, f=t&63) over rows [rg*64,+64)
    {
        const int rg = t >> 8, kg = (t >> 6) & 3, f = t & 63;
        const float* xp = x_to_pool + (size_t)b * NN * (64 * DIMS) + f * DIMS + d;
        float xa0 = 0.f, xa1 = 0.f, xa2 = 0.f, xa3 = 0.f;
        const int n0 = rg * 64;
        #pragma unroll 4
        for (int n = n0; n < n0 + 64; ++n) {
            const float xv = xp[(size_t)n * (64 * DIMS)];
            const float4 s4 = *(const float4*)(hbf + SL_OFF + n * 20 + kg * 4);
            xa0 += xv * s4.x; xa1 += xv * s4.y; xa2 += xv * s4.z; xa3 += xv * s4.w;
        }
        float4 v; v.x = xa0; v.y = xa1; v.z = xa2; v.w = xa3;
        *(float4*)(hbf + PXP_OFF + ((rg * 4 + kg) * 64 + f) * 4) = v;
    }
    __syncthreads();   // [B9] padj + px partials visible

    // Phase D merges (deterministic fixed-order sums)
    if (t < 256) {     // pea: (k,l) = (t>>4, t&15)
        const float v = (hbf[PJW_OFF + t] + hbf[PJW_OFF + 256 + t]
                       + hbf[PJW_OFF + 512 + t] + hbf[PJW_OFF + 768 + t]) * (1.f / 256.f);
        out[PEA_OFF + (size_t)((b * KK + (t >> 4)) * KK + (t & 15)) * DIMS + d] = v;
    }
    {                  // px: (k,f) = (t>>6, t&63)
        const int k = t >> 6, f = t & 63;
        const int kg = k >> 2, e = k & 3;
        float s = 0.f;
        #pragma unroll
        for (int rg = 0; rg < 4; ++rg)
            s += hbf[PXP_OFF + ((rg * 4 + kg) * 64 + f) * 4 + e];
        out[PX_OFF + ((size_t)((b * KK + k) * 64) + f) * DIMS + d] = s * (1.f / 16.f);
    }
}

__global__ void aux_kernel(float* __restrict__ out)
{
    const int idx = blockIdx.x * 256 + threadIdx.x;
    if (idx < 2 * NTOT) {
        const int r = idx & (NTOT - 1);
        const int bb = r >> 8;
        const int j = r & 255;
        const int v = (idx < NTOT) ? (bb * KK + (j >> 4)) : (bb * KK + (j & 15));
        out[PEI_OFF + idx] = (float)v;
    } else if (idx < 2 * NTOT + NB * KK) {
        const int i = idx - 2 * NTOT;
        out[PB_OFF + i] = (float)(i >> 4);
    }
}

__global__ void loss_kernel(const float* __restrict__ entpart,
                            const float* __restrict__ modpart,
                            float* __restrict__ out)
{
    const int tid = threadIdx.x;
    float e = 0.f, m = 0.f;
    for (int i = tid; i < DIMS * NB; i += 256) { e += entpart[i]; m += modpart[i]; }
    #pragma unroll
    for (int off = 32; off; off >>= 1) { e += __shfl_down(e, off); m += __shfl_down(m, off); }
    __shared__ float er[4], mr[4];
    const int wave = tid >> 6, lane = tid & 63;
    if (lane == 0) { er[wave] = e; mr[wave] = m; }
    __syncthreads();
    if (tid == 0) {
        const float es = er[0] + er[1] + er[2] + er[3];
        const float ms = mr[0] + mr[1] + mr[2] + mr[3];
        out[LOSS_OFF] = ms / (float)NE + es / (float)(DIMS * NTOT);
    }
}

extern "C" void kernel_launch(void* const* d_in, const int* in_sizes, int n_in,
                              void* d_out, int out_size, void* d_ws, size_t ws_size,
                              hipStream_t stream)
{
    const float* x         = (const float*)d_in[0];
    const float* edge_attr = (const float*)d_in[1];
    const float* x_to_pool = (const float*)d_in[2];
    const float* Wm0 = (const float*)d_in[3];
    const float* Ws0 = (const float*)d_in[4];
    const float* b0  = (const float*)d_in[5];
    const float* Wm1 = (const float*)d_in[6];
    const float* Ws1 = (const float*)d_in[7];
    const float* b1  = (const float*)d_in[8];
    const float* Wm2 = (const float*)d_in[9];
    const float* Ws2 = (const float*)d_in[10];
    const float* b2  = (const float*)d_in[11];
    const float* fcW1= (const float*)d_in[12];
    const float* fcb1= (const float*)d_in[13];
    const float* fcW2= (const float*)d_in[14];
    const float* fcb2= (const float*)d_in[15];
    const int* edge_index = (const int*)d_in[16];
    float* out = (float*)d_out;
    char* ws = (char*)d_ws;
    float*         wrec  = (float*)(ws + WREC_WS);
    unsigned char* clrec = (unsigned char*)(ws + CLREC_WS);
    int*           iptr  = (int*)(ws + IPTR_WS);
    float*         entpart = (float*)(ws + ENT_WS);
    float*         modpart = (float*)(ws + MOD_WS);
    float*         wc    = (float*)(ws + WC_WS);
    float*         bc    = (float*)(ws + BC_WS);

    csr_build<<<dim3(NB), dim3(256), 0, stream>>>(edge_index, edge_attr, wrec, clrec, iptr);
    fc_combine<<<dim3(1), dim3(256), 0, stream>>>(fcW1, fcb1, fcW2, fcb2, wc, bc);
    gconv_kernel<<<dim3(DIMS * NB), dim3(1024), 0, stream>>>(
        x, x_to_pool, Wm0, Ws0, b0, Wm1, Ws1, b1, Wm2, Ws2, b2,
        wc, bc, wrec, clrec, iptr, out, entpart, modpart);
    aux_kernel<<<dim3((2 * NTOT + NB * KK + 255) / 256), dim3(256), 0, stream>>>(out);
    loss_kernel<<<dim3(1), dim3(256), 0, stream>>>(entpart, modpart, out);
}